// Round 3
// baseline (3740.262 us; speedup 1.0000x reference)
//
#include <hip/hip_runtime.h>
#include <cstddef>

#define EPSV 1e-5f

typedef __attribute__((ext_vector_type(8))) short frag8;   // 8 bf16 (4 VGPRs)
typedef __attribute__((ext_vector_type(4))) float f32x4;   // MFMA acc

__device__ __forceinline__ float lrelu01(float v) { return v > 0.f ? v : 0.01f * v; }
__device__ __forceinline__ void atomAddF(float* p, float v) { unsafeAtomicAdd(p, v); }
__device__ __forceinline__ unsigned fkey(float f) {
    unsigned u = __float_as_uint(f);
    return (u & 0x80000000u) ? ~u : (u | 0x80000000u);
}
__device__ __forceinline__ unsigned short f2b(float f) {  // RNE float->bf16
    unsigned u = __float_as_uint(f);
    unsigned r = u + 0x7fffu + ((u >> 16) & 1u);
    return (unsigned short)(r >> 16);
}
__device__ __forceinline__ float b2f(unsigned short h) {
    return __uint_as_float(((unsigned)h) << 16);
}

static inline unsigned cdivu(unsigned a, unsigned b) { return (a + b - 1) / b; }

// ---------------- small kernels ----------------

__global__ void k_deg(const int* __restrict__ dst, int* __restrict__ deg, int E) {
    int e = blockIdx.x * 256 + threadIdx.x;
    if (e < E) atomicAdd(&deg[dst[e]], 1);
}

__global__ void k_dinv(const int* __restrict__ deg, float* __restrict__ dinv, int n) {
    int i = blockIdx.x * 256 + threadIdx.x;
    if (i < n) dinv[i] = rsqrtf((float)(deg[i] + 1));  // +1 self loop
}

// convert all 8 GEMM weight matrices fp32 -> bf16 into one packed region
__global__ void k_wconv(const float* __restrict__ s0, const float* __restrict__ s1,
                        const float* __restrict__ s2, const float* __restrict__ s3,
                        const float* __restrict__ s4, const float* __restrict__ s5,
                        const float* __restrict__ s6, const float* __restrict__ s7,
                        unsigned short* __restrict__ dst) {
    int t = blockIdx.x * 256 + threadIdx.x;
    if (t >= 278528) return;
    const float* srcs[8] = {s0, s1, s2, s3, s4, s5, s6, s7};
    const int off[9] = {0, 8192, 139264, 143360, 147456, 163840, 180224, 196608, 278528};
    int seg = 0;
    while (t >= off[seg + 1]) ++seg;
    dst[t] = f2b(srcs[seg][t - off[seg]]);
}

// h1 = relu(x @ c1w.T + c1b) -> bf16 [N,64]
__global__ void k_h1(const float* __restrict__ x, const float* __restrict__ w,
                     const float* __restrict__ b, unsigned short* __restrict__ h1, int n) {
    int t = blockIdx.x * 256 + threadIdx.x;
    int node = t >> 6, c = t & 63;
    if (node >= n) return;
    float x0 = x[node * 3], x1 = x[node * 3 + 1], x2 = x[node * 3 + 2];
    float v = x0 * w[c * 3] + x1 * w[c * 3 + 1] + x2 * w[c * 3 + 2] + b[c];
    h1[(size_t)node * 64 + c] = f2b(fmaxf(v, 0.f));
}

__global__ void k_murs(const float* __restrict__ sum2, const float* __restrict__ ss2,
                       float* __restrict__ mu2, float* __restrict__ rs2, float invn) {
    int c = threadIdx.x;  // 128
    float m = sum2[c] * invn;
    float var = ss2[c] * invn - m * m;
    mu2[c] = m;
    rs2[c] = rsqrtf(var + EPSV);
}

// A3 = bf16(relu((z2 - mu)*rs)), z2 fp32 [N,128]
__global__ void k_prebn(const float* __restrict__ z, const float* __restrict__ mu,
                        const float* __restrict__ rs, unsigned short* __restrict__ a3,
                        int total) {
    int t = (blockIdx.x * 256 + threadIdx.x) * 4;
    if (t >= total) return;
    int c = t & 127;
    float4 v = *(const float4*)(z + t);
    ushort4 o;
    o.x = f2b(fmaxf((v.x - mu[c + 0]) * rs[c + 0], 0.f));
    o.y = f2b(fmaxf((v.y - mu[c + 1]) * rs[c + 1], 0.f));
    o.z = f2b(fmaxf((v.z - mu[c + 2]) * rs[c + 2], 0.f));
    o.w = f2b(fmaxf((v.w - mu[c + 3]) * rs[c + 3], 0.f));
    *(ushort4*)(a3 + t) = o;
}

// g[c] = relu((max_c - mu_c) * rsqrt(var_c + eps)), c in [0,1024)
__global__ void k_g(const float* __restrict__ sum3, const float* __restrict__ ss3,
                    const unsigned* __restrict__ maxk, float* __restrict__ g, float invn) {
    int c = blockIdx.x * 256 + threadIdx.x;
    float m = sum3[c] * invn;
    float var = ss3[c] * invn - m * m;
    unsigned k = maxk[c];
    unsigned u = (k & 0x80000000u) ? (k & 0x7FFFFFFFu) : ~k;
    g[c] = fmaxf((__uint_as_float(u) - m) * rsqrtf(var + EPSV), 0.f);
}

// fc1: a1[row] = relu(f1w[row,:] @ g + f1b[row]); grid 8 x 256, 4 threads/row
__global__ void k_fc1(const float* __restrict__ g, const float* __restrict__ f1w,
                      const float* __restrict__ f1b, float* __restrict__ a1) {
    int row = blockIdx.x * 64 + (threadIdx.x >> 2);
    int part = threadIdx.x & 3;
    const float* w = f1w + (size_t)row * 1024 + part * 256;
    const float* gg = g + part * 256;
    float s = 0.f;
    for (int k = 0; k < 256; ++k) s = fmaf(w[k], gg[k], s);
    s += __shfl_xor(s, 1); s += __shfl_xor(s, 2);
    if (part == 0) a1[row] = fmaxf(s + f1b[row], 0.f);
}

__launch_bounds__(256)
__global__ void k_fc23(const float* __restrict__ a1, const float* __restrict__ f2w,
                       const float* __restrict__ f2b, const float* __restrict__ f3w,
                       const float* __restrict__ f3b, float* __restrict__ T9) {
    __shared__ float a2[256];
    int tid = threadIdx.x;
    {
        const float* w = f2w + (size_t)tid * 512;
        float s = f2b[tid];
        for (int k = 0; k < 512; ++k) s = fmaf(w[k], a1[k], s);
        a2[tid] = fmaxf(s, 0.f);
    }
    __syncthreads();
    if (tid < 9) {
        const float* w = f3w + (size_t)tid * 256;
        float s = f3b[tid];
        for (int k = 0; k < 256; ++k) s = fmaf(w[k], a2[k], s);
        if (tid == 0 || tid == 4 || tid == 8) s += 1.f;
        T9[tid] = s;
    }
}

// xg = lrelu((x@T) @ conv1w.T + b) -> bf16 into hcat cols 256.. (ushort stride 320)
__global__ void k_xg(const float* __restrict__ x, const float* __restrict__ T9,
                     const float* __restrict__ w, const float* __restrict__ b,
                     unsigned short* __restrict__ xg, int n) {
    int t = blockIdx.x * 256 + threadIdx.x;
    int node = t >> 6, c = t & 63;
    if (node >= n) return;
    float x0 = x[node * 3], x1 = x[node * 3 + 1], x2 = x[node * 3 + 2];
    float h0 = x0 * T9[0] + x1 * T9[3] + x2 * T9[6];
    float h1 = x0 * T9[1] + x1 * T9[4] + x2 * T9[7];
    float h2 = x0 * T9[2] + x1 * T9[5] + x2 * T9[8];
    float v = h0 * w[c * 3] + h1 * w[c * 3 + 1] + h2 * w[c * 3 + 2] + b[c];
    xg[(size_t)node * 320 + c] = f2b(lrelu01(v));
}

// scatter-add q[src] into agg[dst], float4 per thread. C=64 -> 16 lanes/edge, C=128 -> 32
template <int C>
__global__ void k_scatter4(const int* __restrict__ src, const int* __restrict__ dst,
                           const float* __restrict__ q, float* __restrict__ agg, int E) {
    constexpr int SH = (C == 64) ? 4 : 5;
    int t = blockIdx.x * 256 + threadIdx.x;
    int e = t >> SH;
    int sub = (t & ((C / 4) - 1)) * 4;
    if (e >= E) return;
    int s = src[e], d = dst[e];
    float4 v = *(const float4*)(q + (size_t)s * C + sub);
    float* p = agg + (size_t)d * C + sub;
    atomAddF(p + 0, v.x); atomAddF(p + 1, v.y);
    atomAddF(p + 2, v.z); atomAddF(p + 3, v.w);
}

// LN over concat[nf(bf16), lrelu(dinv*(agg+q)+gcn_b)]; wave per node; bf16 out
template <int CH>
__launch_bounds__(256)
__global__ void k_ln(const unsigned short* __restrict__ nf, const float* __restrict__ agg,
                     const float* __restrict__ q, const float* __restrict__ dinv,
                     const float* __restrict__ gcn_b, const float* __restrict__ lng,
                     const float* __restrict__ lnb, unsigned short* __restrict__ out,
                     int ldo, int n) {
    int wv = threadIdx.x >> 6, lane = threadIdx.x & 63;
    int node = blockIdx.x * 4 + wv;
    if (node >= n) return;
    float di = dinv[node];
    constexpr int R = CH / 64;
    float vA[R], vB[R];
    float s = 0.f, ss = 0.f;
#pragma unroll
    for (int r = 0; r < R; ++r) {
        int c = lane + r * 64;
        float a = b2f(nf[(size_t)node * CH + c]);
        float b = di * (agg[(size_t)node * CH + c] + q[(size_t)node * CH + c]) + gcn_b[c];
        b = lrelu01(b);
        vA[r] = a; vB[r] = b;
        s += a + b; ss += a * a + b * b;
    }
#pragma unroll
    for (int off = 32; off > 0; off >>= 1) {
        s += __shfl_down(s, off);
        ss += __shfl_down(ss, off);
    }
    s = __shfl(s, 0); ss = __shfl(ss, 0);
    const float inv2c = 1.f / (float)(2 * CH);
    float m = s * inv2c;
    float var = ss * inv2c - m * m;
    float rsg = rsqrtf(var + EPSV);
#pragma unroll
    for (int r = 0; r < R; ++r) {
        int c = lane + r * 64;
        out[(size_t)node * ldo + c] = f2b((vA[r] - m) * rsg * lng[c] + lnb[c]);
        out[(size_t)node * ldo + CH + c] = f2b((vB[r] - m) * rsg * lng[CH + c] + lnb[CH + c]);
    }
}

__global__ void k_const4(const float* __restrict__ pooled, const float* __restrict__ ow,
                         const float* __restrict__ ob, float* __restrict__ c4, float invn) {
    int j = threadIdx.x >> 6, lane = threadIdx.x & 63;
    float s = 0.f;
    for (int c = lane; c < 256; c += 64) s += pooled[c] * invn * ow[j * 320 + c];
#pragma unroll
    for (int off = 32; off > 0; off >>= 1) s += __shfl_down(s, off);
    if (lane == 0) c4[j] = s + ob[j];
}

__global__ void k_out(const unsigned short* __restrict__ hcat, const float* __restrict__ ow,
                      const float* __restrict__ c4, float* __restrict__ out, int n) {
    int t = blockIdx.x * 256 + threadIdx.x;
    int node = t >> 2, j = t & 3;
    if (node >= n) return;
    const unsigned short* xg = hcat + (size_t)node * 320 + 256;
    const float* w = ow + j * 320 + 256;
    float s = c4[j];
#pragma unroll
    for (int k = 0; k < 64; ++k) s = fmaf(b2f(xg[k]), w[k], s);
    out[(size_t)node * 4 + j] = s;
}

// ---------------- MFMA bf16 GEMM ----------------
// Out[n][c] = epi(sum_k A[n][k] * W[c][k] + b[c]); A,W bf16, acc fp32.
// BM=128 nodes/block, BN columns/block, 256 threads = 4 waves.
enum { MF_BIAS = 1, MF_LRELU = 2, MF_DINV = 4, MF_STOREF = 8, MF_STOREB = 16,
       MF_STATS = 32, MF_COLSUM = 64 };

template <int BN, int MODE>
__launch_bounds__(256)
__global__ void k_mgemm(const unsigned short* __restrict__ A, int lda, int K,
                        const unsigned short* __restrict__ W,  // [C][K]
                        const float* __restrict__ bias,
                        float* __restrict__ OutF, unsigned short* __restrict__ OutB, int ldo,
                        const float* __restrict__ dinv,
                        float* __restrict__ sum_o, float* __restrict__ ss_o,
                        unsigned* __restrict__ maxk_o) {
    constexpr int BM = 128;
    constexpr int LDT = 40;  // ushort stride per 32-k row: 20 words -> 2-way banks (free)
    __shared__ unsigned short As[BM * LDT];
    __shared__ unsigned short Ws[BN * LDT];
    __shared__ float redS[2 * 128];
    __shared__ unsigned redM[128];

    const int tid = threadIdx.x;
    const int wid = tid >> 6, lane = tid & 63;
    const int quad = lane >> 4, lrow = lane & 15;
    const int bn0 = blockIdx.x * BM;
    const int bc0 = blockIdx.y * BN;

    constexpr int NI = (BN == 128) ? 4 : 2;  // wave m-subtiles (16 rows each)
    constexpr int NJ = 4;                    // wave n-subtiles
    const int wm = (BN == 128) ? (wid & 1) * 64 : wid * 32;
    const int wn = (BN == 128) ? (wid >> 1) * 64 : 0;

    if (MODE & (MF_STATS | MF_COLSUM)) {
        for (int c = tid; c < BN; c += 256) {
            redS[c] = 0.f; redS[128 + c] = 0.f; redM[c] = 0u;
        }
    }

    f32x4 acc[NI][NJ] = {};

    for (int k0 = 0; k0 < K; k0 += 32) {
        // stage A tile: BM rows x 32 k (4 x 16B chunks per row)
#pragma unroll
        for (int h = 0; h < 2; ++h) {
            int ch = tid + h * 256;
            int row = ch >> 2, cp = ch & 3;
            const unsigned short* src = A + (size_t)(bn0 + row) * lda + k0 + cp * 8;
            *(float4*)&As[row * LDT + cp * 8] = *(const float4*)src;
        }
        // stage W tile
#pragma unroll
        for (int h = 0; h < BN / 64; ++h) {
            int ch = tid + h * 256;
            int row = ch >> 2, cp = ch & 3;
            const unsigned short* src = W + (size_t)(bc0 + row) * K + k0 + cp * 8;
            *(float4*)&Ws[row * LDT + cp * 8] = *(const float4*)src;
        }
        __syncthreads();
        frag8 af[NI], bf[NJ];
#pragma unroll
        for (int i = 0; i < NI; ++i)
            af[i] = *(const frag8*)&As[(wm + i * 16 + lrow) * LDT + quad * 8];
#pragma unroll
        for (int j = 0; j < NJ; ++j)
            bf[j] = *(const frag8*)&Ws[(wn + j * 16 + lrow) * LDT + quad * 8];
#pragma unroll
        for (int i = 0; i < NI; ++i)
#pragma unroll
            for (int j = 0; j < NJ; ++j)
                acc[i][j] = __builtin_amdgcn_mfma_f32_16x16x32_bf16(af[i], bf[j], acc[i][j], 0, 0, 0);
        __syncthreads();
    }

    // epilogue: C/D layout col=lane&15, row=quad*4+reg
#pragma unroll
    for (int j = 0; j < NJ; ++j) {
        const int col = bc0 + wn + j * 16 + lrow;
        float bv = (MODE & MF_BIAS) ? bias[col] : 0.f;
        float s = 0.f, q = 0.f, m = -3.4e38f;
#pragma unroll
        for (int i = 0; i < NI; ++i) {
            const int rowb = bn0 + wm + i * 16 + quad * 4;
#pragma unroll
            for (int r = 0; r < 4; ++r) {
                float t = acc[i][j][r] + bv;
                if (MODE & MF_LRELU) t = lrelu01(t);
                if (MODE & MF_DINV) t *= dinv[rowb + r];
                if (MODE & MF_STOREF) OutF[(size_t)(rowb + r) * ldo + col] = t;
                if (MODE & MF_STOREB) OutB[(size_t)(rowb + r) * ldo + col] = f2b(t);
                s += t; q += t * t; m = fmaxf(m, t);
            }
        }
        if (MODE & (MF_STATS | MF_COLSUM)) {
            s += __shfl_xor(s, 16); s += __shfl_xor(s, 32);
            if (MODE & MF_STATS) {
                q += __shfl_xor(q, 16); q += __shfl_xor(q, 32);
                m = fmaxf(m, __shfl_xor(m, 16)); m = fmaxf(m, __shfl_xor(m, 32));
            }
            if (quad == 0) {
                int lc = wn + j * 16 + lrow;
                atomicAdd(&redS[lc], s);
                if (MODE & MF_STATS) {
                    atomicAdd(&redS[128 + lc], q);
                    atomicMax(&redM[lc], fkey(m));
                }
            }
        }
    }
    if (MODE & (MF_STATS | MF_COLSUM)) {
        __syncthreads();
        for (int c = tid; c < BN; c += 256) {
            atomAddF(&sum_o[bc0 + c], redS[c]);
            if (MODE & MF_STATS) {
                atomAddF(&ss_o[bc0 + c], redS[128 + c]);
                atomicMax(&maxk_o[bc0 + c], redM[c]);
            }
        }
    }
}

// ---------------- launch ----------------
// ws layout (~185 MB): deg[N]i32 | dinv[N]f32 | sm[8192]f32 | WB[278528+pad]u16 |
//   H[N,320]u16 (hcat: LN2 out cols 0..255, xg cols 256..319) |
//   F1[N,128]f32 (z2 -> q1|agg1 -> q2) | F2[N,128]f32 (agg2) |
//   B1[N,64]u16 (h1 -> nf1) | B2[N,128]u16 (A3 -> hln1 -> nf2) | B3[N,128]u16 (hmid)

extern "C" void kernel_launch(void* const* d_in, const int* in_sizes, int n_in,
                              void* d_out, int out_size, void* d_ws, size_t ws_size,
                              hipStream_t stream) {
    const float* x   = (const float*)d_in[0];
    const int*   ei  = (const int*)d_in[1];
    const float* c1w = (const float*)d_in[2];  const float* c1b = (const float*)d_in[3];
    const float* c2w = (const float*)d_in[4];  const float* c2b = (const float*)d_in[5];
    const float* c3w = (const float*)d_in[6];  const float* c3b = (const float*)d_in[7];
    const float* f1w = (const float*)d_in[8];  const float* f1b = (const float*)d_in[9];
    const float* f2w = (const float*)d_in[10]; const float* f2b = (const float*)d_in[11];
    const float* f3w = (const float*)d_in[12]; const float* f3b = (const float*)d_in[13];
    const float* cv1w = (const float*)d_in[14]; const float* cv1b = (const float*)d_in[15];
    const float* li1w = (const float*)d_in[16]; const float* li1b = (const float*)d_in[17];
    const float* gc1w = (const float*)d_in[18]; const float* gc1b = (const float*)d_in[19];
    const float* ln1g = (const float*)d_in[20]; const float* ln1b = (const float*)d_in[21];
    const float* cv2w = (const float*)d_in[22]; const float* cv2b = (const float*)d_in[23];
    const float* li2w = (const float*)d_in[24]; const float* li2b = (const float*)d_in[25];
    const float* gc2w = (const float*)d_in[26]; const float* gc2b = (const float*)d_in[27];
    const float* ln2g = (const float*)d_in[28]; const float* ln2b = (const float*)d_in[29];
    const float* cv3w = (const float*)d_in[30]; const float* cv3b = (const float*)d_in[31];
    const float* ow  = (const float*)d_in[32]; const float* ob  = (const float*)d_in[33];
    float* out = (float*)d_out;

    const int N = in_sizes[0] / 3;
    const int E = in_sizes[1] / 2;
    const int* srcI = ei;
    const int* dstI = ei + E;

    char* base = (char*)d_ws;
    size_t off = 0;
    auto take = [&](size_t bytes) -> char* {
        char* p = base + off;
        off = (off + bytes + 255) & ~(size_t)255;
        return p;
    };
    int*   deg  = (int*)  take((size_t)N * 4);
    float* dinv = (float*)take((size_t)N * 4);
    float* sm   = (float*)take(8192 * 4);
    unsigned short* WB = (unsigned short*)take(278528 * 2);
    unsigned short* H  = (unsigned short*)take((size_t)N * 320 * 2);
    float* F1 = (float*)take((size_t)N * 128 * 4);
    float* F2 = (float*)take((size_t)N * 128 * 4);
    unsigned short* B1 = (unsigned short*)take((size_t)N * 64 * 2);
    unsigned short* B2 = (unsigned short*)take((size_t)N * 128 * 2);
    unsigned short* B3 = (unsigned short*)take((size_t)N * 128 * 2);

    // bf16 weights inside WB
    unsigned short* c2wb  = WB + 0;
    unsigned short* c3wb  = WB + 8192;
    unsigned short* li1wb = WB + 139264;
    unsigned short* gc1wb = WB + 143360;
    unsigned short* cv2wb = WB + 147456;
    unsigned short* li2wb = WB + 163840;
    unsigned short* gc2wb = WB + 180224;
    unsigned short* cv3wb = WB + 196608;

    // sm layout (floats): [0,3712) zeroed
    float* sum2 = sm + 0;    float* ss2 = sm + 128;
    float* sum3 = sm + 256;  float* ss3 = sm + 1280;
    unsigned* maxk = (unsigned*)(sm + 2304);   // 1024
    float* pooled = sm + 3328;                 // 256
    unsigned* dmax = (unsigned*)(sm + 3584);   // 128 dummy max for z2 stats
    float* mu2 = sm + 3712; float* rs2 = sm + 3840;
    float* T9  = sm + 3968; float* c4 = sm + 3984;
    float* gbuf = sm + 4096;  // 1024
    float* a1   = sm + 5120;  // 512

    const float invn = 1.0f / (float)N;
    const dim3 blk(256);
    const unsigned GX = (unsigned)(N / 128);  // 625

    hipMemsetAsync(deg, 0, (size_t)N * 4, stream);
    hipMemsetAsync(sm, 0, 3712 * 4, stream);

    k_deg<<<cdivu(E, 256), blk, 0, stream>>>(dstI, deg, E);
    k_dinv<<<cdivu(N, 256), blk, 0, stream>>>(deg, dinv, N);
    k_wconv<<<cdivu(278528, 256), blk, 0, stream>>>(c2w, c3w, li1w, gc1w, cv2w, li2w, gc2w, cv3w, WB);

    // ---- TNet ----
    k_h1<<<cdivu((unsigned)N * 64, 256), blk, 0, stream>>>(x, c1w, c1b, B1, N);
    // z2 = h1 @ c2w.T + c2b  (store fp32 + fused BN colstats)
    k_mgemm<128, (MF_BIAS | MF_STOREF | MF_STATS)><<<dim3(GX, 1), blk, 0, stream>>>(
        B1, 64, 64, c2wb, c2b, F1, nullptr, 128, nullptr, sum2, ss2, dmax);
    k_murs<<<1, 128, 0, stream>>>(sum2, ss2, mu2, rs2, invn);
    k_prebn<<<cdivu((unsigned)N * 128 / 4, 256), blk, 0, stream>>>(F1, mu2, rs2, B2, N * 128);
    // z3 stats (sum/ss/max per channel), no store
    k_mgemm<128, (MF_BIAS | MF_STATS)><<<dim3(GX, 8), blk, 0, stream>>>(
        B2, 128, 128, c3wb, c3b, nullptr, nullptr, 0, nullptr, sum3, ss3, maxk);
    k_g<<<4, blk, 0, stream>>>(sum3, ss3, maxk, gbuf, invn);
    k_fc1<<<8, blk, 0, stream>>>(gbuf, f1w, f1b, a1);
    k_fc23<<<1, blk, 0, stream>>>(a1, f2w, f2b, f3w, f3b, T9);
    k_xg<<<cdivu((unsigned)N * 64, 256), blk, 0, stream>>>(x, T9, cv1w, cv1b, H + 256, N);

    // ---- GCN block 1 (C=64) ----
    k_mgemm<64, (MF_BIAS | MF_LRELU | MF_STOREB)><<<dim3(GX, 1), blk, 0, stream>>>(
        H + 256, 320, 64, li1wb, li1b, nullptr, B1, 64, nullptr, nullptr, nullptr, nullptr);
    k_mgemm<64, (MF_DINV | MF_STOREF)><<<dim3(GX, 1), blk, 0, stream>>>(
        B1, 64, 64, gc1wb, nullptr, F1, nullptr, 64, dinv, nullptr, nullptr, nullptr);
    hipMemsetAsync(F1 + (size_t)N * 64, 0, (size_t)N * 64 * 4, stream);  // agg1
    k_scatter4<64><<<cdivu((unsigned)E * 16, 256), blk, 0, stream>>>(srcI, dstI, F1, F1 + (size_t)N * 64, E);
    k_ln<64><<<cdivu(N, 4), blk, 0, stream>>>(B1, F1 + (size_t)N * 64, F1, dinv, gc1b, ln1g, ln1b, B2, 128, N);
    k_mgemm<128, (MF_BIAS | MF_LRELU | MF_STOREB)><<<dim3(GX, 1), blk, 0, stream>>>(
        B2, 128, 128, cv2wb, cv2b, nullptr, B3, 128, nullptr, nullptr, nullptr, nullptr);

    // ---- GCN block 2 (C=128) ----
    k_mgemm<128, (MF_BIAS | MF_LRELU | MF_STOREB)><<<dim3(GX, 1), blk, 0, stream>>>(
        B3, 128, 128, li2wb, li2b, nullptr, B2, 128, nullptr, nullptr, nullptr, nullptr);
    k_mgemm<128, (MF_DINV | MF_STOREF)><<<dim3(GX, 1), blk, 0, stream>>>(
        B2, 128, 128, gc2wb, nullptr, F1, nullptr, 128, dinv, nullptr, nullptr, nullptr);
    hipMemsetAsync(F2, 0, (size_t)N * 128 * 4, stream);  // agg2
    k_scatter4<128><<<cdivu((unsigned)E * 32, 256), blk, 0, stream>>>(srcI, dstI, F1, F2, E);
    k_ln<128><<<cdivu(N, 4), blk, 0, stream>>>(B2, F2, F1, dinv, gc2b, ln2g, ln2b, H, 320, N);

    // ---- conv3 (K=320 -> 256) fused column-sum only ----
    k_mgemm<128, (MF_BIAS | MF_LRELU | MF_COLSUM)><<<dim3(GX, 2), blk, 0, stream>>>(
        H, 320, 320, cv3wb, cv3b, nullptr, nullptr, 0, nullptr, pooled, nullptr, nullptr);

    // ---- head ----
    k_const4<<<1, 256, 0, stream>>>(pooled, ow, ob, c4, invn);
    k_out<<<cdivu((unsigned)N * 4, 256), blk, 0, stream>>>(H, ow, c4, out, N);
}

// Round 4
// 835.205 us; speedup vs baseline: 4.4783x; 4.4783x over previous
//
#include <hip/hip_runtime.h>
#include <cstddef>

#define EPSV 1e-5f

typedef __attribute__((ext_vector_type(8))) short frag8;   // 8 bf16 (4 VGPRs)
typedef __attribute__((ext_vector_type(4))) float f32x4;   // MFMA acc

__device__ __forceinline__ float lrelu01(float v) { return v > 0.f ? v : 0.01f * v; }
__device__ __forceinline__ void atomAddF(float* p, float v) { unsafeAtomicAdd(p, v); }
__device__ __forceinline__ unsigned fkey(float f) {
    unsigned u = __float_as_uint(f);
    return (u & 0x80000000u) ? ~u : (u | 0x80000000u);
}
__device__ __forceinline__ unsigned short f2b(float f) {  // RNE float->bf16
    unsigned u = __float_as_uint(f);
    unsigned r = u + 0x7fffu + ((u >> 16) & 1u);
    return (unsigned short)(r >> 16);
}
__device__ __forceinline__ float b2f(unsigned short h) {
    return __uint_as_float(((unsigned)h) << 16);
}

static inline unsigned cdivu(unsigned a, unsigned b) { return (a + b - 1) / b; }

// ---------------- graph prep: degree, dinv, CSR build ----------------

__global__ void k_deg(const int* __restrict__ dst, int* __restrict__ deg, int E) {
    int e = blockIdx.x * 256 + threadIdx.x;
    if (e < E) atomicAdd(&deg[dst[e]], 1);
}

__global__ void k_dinv(const int* __restrict__ deg, float* __restrict__ dinv, int n) {
    int i = blockIdx.x * 256 + threadIdx.x;
    if (i < n) dinv[i] = rsqrtf((float)(deg[i] + 1));  // +1 self loop
}

// per-block exclusive scan of deg -> startv (local), block sums -> bsum
__global__ void k_scan_local(const int* __restrict__ deg, int* __restrict__ startv,
                             int* __restrict__ bsum, int n) {
    __shared__ int t0[256];
    int tid = threadIdx.x;
    int i = blockIdx.x * 256 + tid;
    int v = (i < n) ? deg[i] : 0;
    t0[tid] = v;
    __syncthreads();
    for (int o = 1; o < 256; o <<= 1) {
        int add = (tid >= o) ? t0[tid - o] : 0;
        __syncthreads();
        t0[tid] += add;
        __syncthreads();
    }
    if (i < n) startv[i] = t0[tid] - v;
    if (tid == 255) bsum[blockIdx.x] = t0[255];
}

// single block of 512: exclusive scan of bsum[nb] in place (nb <= 512)
__global__ void k_scan_bsum(int* __restrict__ bsum, int nb) {
    __shared__ int t0[512];
    int tid = threadIdx.x;
    int v = (tid < nb) ? bsum[tid] : 0;
    t0[tid] = v;
    __syncthreads();
    for (int o = 1; o < 512; o <<= 1) {
        int add = (tid >= o) ? t0[tid - o] : 0;
        __syncthreads();
        t0[tid] += add;
        __syncthreads();
    }
    if (tid < nb) bsum[tid] = t0[tid] - v;
}

__global__ void k_scan_add(int* __restrict__ startv, const int* __restrict__ bsum,
                           int* __restrict__ cursor, int n) {
    int i = blockIdx.x * 256 + threadIdx.x;
    if (i < n) {
        int s = startv[i] + bsum[blockIdx.x];
        startv[i] = s;
        cursor[i] = s;
    }
}

__global__ void k_fill(const int* __restrict__ src, const int* __restrict__ dst,
                       int* __restrict__ cursor, int* __restrict__ csr, int E) {
    int e = blockIdx.x * 256 + threadIdx.x;
    if (e < E) {
        int pos = atomicAdd(&cursor[dst[e]], 1);
        csr[pos] = src[e];
    }
}

// gather: agg[d] = q[d] + sum_{s in neigh(d)} q[s]; q bf16, agg fp32. wave per node.
template <int CH>
__launch_bounds__(256)
__global__ void k_gather(const int* __restrict__ startv, const int* __restrict__ deg,
                         const int* __restrict__ csr, const unsigned short* __restrict__ q,
                         float* __restrict__ agg, int n) {
    int wid = threadIdx.x >> 6, lane = threadIdx.x & 63;
    int node = blockIdx.x * 4 + wid;
    if (node >= n) return;
    constexpr int V = CH / 64;  // floats per lane (1 or 2)
    float a0, a1;
    if (V == 1) {
        a0 = b2f(q[(size_t)node * CH + lane]); a1 = 0.f;
    } else {
        unsigned u = *(const unsigned*)(q + (size_t)node * CH + lane * 2);
        a0 = __uint_as_float((u & 0xffffu) << 16);
        a1 = __uint_as_float(u & 0xffff0000u);
    }
    int s0 = startv[node], cnt = deg[node];
    for (int j = 0; j < cnt; ++j) {
        int s = csr[s0 + j];
        if (V == 1) {
            a0 += b2f(q[(size_t)s * CH + lane]);
        } else {
            unsigned u = *(const unsigned*)(q + (size_t)s * CH + lane * 2);
            a0 += __uint_as_float((u & 0xffffu) << 16);
            a1 += __uint_as_float(u & 0xffff0000u);
        }
    }
    if (V == 1) agg[(size_t)node * CH + lane] = a0;
    else *(float2*)(agg + (size_t)node * CH + lane * 2) = make_float2(a0, a1);
}

// ---------------- small kernels ----------------

// convert all 8 GEMM weight matrices fp32 -> bf16 into one packed region
__global__ void k_wconv(const float* __restrict__ s0, const float* __restrict__ s1,
                        const float* __restrict__ s2, const float* __restrict__ s3,
                        const float* __restrict__ s4, const float* __restrict__ s5,
                        const float* __restrict__ s6, const float* __restrict__ s7,
                        unsigned short* __restrict__ dst) {
    int t = blockIdx.x * 256 + threadIdx.x;
    if (t >= 278528) return;
    const float* srcs[8] = {s0, s1, s2, s3, s4, s5, s6, s7};
    const int off[9] = {0, 8192, 139264, 143360, 147456, 163840, 180224, 196608, 278528};
    int seg = 0;
    while (t >= off[seg + 1]) ++seg;
    dst[t] = f2b(srcs[seg][t - off[seg]]);
}

// h1 = relu(x @ c1w.T + c1b) -> bf16 [N,64]
__global__ void k_h1(const float* __restrict__ x, const float* __restrict__ w,
                     const float* __restrict__ b, unsigned short* __restrict__ h1, int n) {
    int t = blockIdx.x * 256 + threadIdx.x;
    int node = t >> 6, c = t & 63;
    if (node >= n) return;
    float x0 = x[node * 3], x1 = x[node * 3 + 1], x2 = x[node * 3 + 2];
    float v = x0 * w[c * 3] + x1 * w[c * 3 + 1] + x2 * w[c * 3 + 2] + b[c];
    h1[(size_t)node * 64 + c] = f2b(fmaxf(v, 0.f));
}

__global__ void k_murs(const float* __restrict__ sum2, const float* __restrict__ ss2,
                       float* __restrict__ mu2, float* __restrict__ rs2, float invn) {
    int c = threadIdx.x;  // 128
    float m = sum2[c] * invn;
    float var = ss2[c] * invn - m * m;
    mu2[c] = m;
    rs2[c] = rsqrtf(var + EPSV);
}

// A3 = bf16(relu((z2 - mu)*rs)), z2 fp32 [N,128]
__global__ void k_prebn(const float* __restrict__ z, const float* __restrict__ mu,
                        const float* __restrict__ rs, unsigned short* __restrict__ a3,
                        int total) {
    int t = (blockIdx.x * 256 + threadIdx.x) * 4;
    if (t >= total) return;
    int c = t & 127;
    float4 v = *(const float4*)(z + t);
    ushort4 o;
    o.x = f2b(fmaxf((v.x - mu[c + 0]) * rs[c + 0], 0.f));
    o.y = f2b(fmaxf((v.y - mu[c + 1]) * rs[c + 1], 0.f));
    o.z = f2b(fmaxf((v.z - mu[c + 2]) * rs[c + 2], 0.f));
    o.w = f2b(fmaxf((v.w - mu[c + 3]) * rs[c + 3], 0.f));
    *(ushort4*)(a3 + t) = o;
}

// g[c] = relu((max_c - mu_c) * rsqrt(var_c + eps)), c in [0,1024)
__global__ void k_g(const float* __restrict__ sum3, const float* __restrict__ ss3,
                    const unsigned* __restrict__ maxk, float* __restrict__ g, float invn) {
    int c = blockIdx.x * 256 + threadIdx.x;
    float m = sum3[c] * invn;
    float var = ss3[c] * invn - m * m;
    unsigned k = maxk[c];
    unsigned u = (k & 0x80000000u) ? (k & 0x7FFFFFFFu) : ~k;
    g[c] = fmaxf((__uint_as_float(u) - m) * rsqrtf(var + EPSV), 0.f);
}

// fc1: a1[row] = relu(f1w[row,:] @ g + f1b[row]); grid 8 x 256, 4 threads/row
__global__ void k_fc1(const float* __restrict__ g, const float* __restrict__ f1w,
                      const float* __restrict__ f1b, float* __restrict__ a1) {
    int row = blockIdx.x * 64 + (threadIdx.x >> 2);
    int part = threadIdx.x & 3;
    const float* w = f1w + (size_t)row * 1024 + part * 256;
    const float* gg = g + part * 256;
    float s = 0.f;
    for (int k = 0; k < 256; ++k) s = fmaf(w[k], gg[k], s);
    s += __shfl_xor(s, 1); s += __shfl_xor(s, 2);
    if (part == 0) a1[row] = fmaxf(s + f1b[row], 0.f);
}

__launch_bounds__(256)
__global__ void k_fc23(const float* __restrict__ a1, const float* __restrict__ f2w,
                       const float* __restrict__ f2b, const float* __restrict__ f3w,
                       const float* __restrict__ f3b, float* __restrict__ T9) {
    __shared__ float a2[256];
    int tid = threadIdx.x;
    {
        const float* w = f2w + (size_t)tid * 512;
        float s = f2b[tid];
        for (int k = 0; k < 512; ++k) s = fmaf(w[k], a1[k], s);
        a2[tid] = fmaxf(s, 0.f);
    }
    __syncthreads();
    if (tid < 9) {
        const float* w = f3w + (size_t)tid * 256;
        float s = f3b[tid];
        for (int k = 0; k < 256; ++k) s = fmaf(w[k], a2[k], s);
        if (tid == 0 || tid == 4 || tid == 8) s += 1.f;
        T9[tid] = s;
    }
}

// xg = lrelu((x@T) @ conv1w.T + b) -> bf16 into hcat cols 256.. (ushort stride 320)
__global__ void k_xg(const float* __restrict__ x, const float* __restrict__ T9,
                     const float* __restrict__ w, const float* __restrict__ b,
                     unsigned short* __restrict__ xg, int n) {
    int t = blockIdx.x * 256 + threadIdx.x;
    int node = t >> 6, c = t & 63;
    if (node >= n) return;
    float x0 = x[node * 3], x1 = x[node * 3 + 1], x2 = x[node * 3 + 2];
    float h0 = x0 * T9[0] + x1 * T9[3] + x2 * T9[6];
    float h1 = x0 * T9[1] + x1 * T9[4] + x2 * T9[7];
    float h2 = x0 * T9[2] + x1 * T9[5] + x2 * T9[8];
    float v = h0 * w[c * 3] + h1 * w[c * 3 + 1] + h2 * w[c * 3 + 2] + b[c];
    xg[(size_t)node * 320 + c] = f2b(lrelu01(v));
}

// LN over concat[nf(bf16), lrelu(dinv*agg + gcn_b)]; agg includes self term. wave/node.
template <int CH>
__launch_bounds__(256)
__global__ void k_ln(const unsigned short* __restrict__ nf, const float* __restrict__ agg,
                     const float* __restrict__ dinv,
                     const float* __restrict__ gcn_b, const float* __restrict__ lng,
                     const float* __restrict__ lnb, unsigned short* __restrict__ out,
                     int ldo, int n) {
    int wv = threadIdx.x >> 6, lane = threadIdx.x & 63;
    int node = blockIdx.x * 4 + wv;
    if (node >= n) return;
    float di = dinv[node];
    constexpr int R = CH / 64;
    float vA[R], vB[R];
    float s = 0.f, ss = 0.f;
#pragma unroll
    for (int r = 0; r < R; ++r) {
        int c = lane + r * 64;
        float a = b2f(nf[(size_t)node * CH + c]);
        float b = di * agg[(size_t)node * CH + c] + gcn_b[c];
        b = lrelu01(b);
        vA[r] = a; vB[r] = b;
        s += a + b; ss += a * a + b * b;
    }
#pragma unroll
    for (int off = 32; off > 0; off >>= 1) {
        s += __shfl_down(s, off);
        ss += __shfl_down(ss, off);
    }
    s = __shfl(s, 0); ss = __shfl(ss, 0);
    const float inv2c = 1.f / (float)(2 * CH);
    float m = s * inv2c;
    float var = ss * inv2c - m * m;
    float rsg = rsqrtf(var + EPSV);
#pragma unroll
    for (int r = 0; r < R; ++r) {
        int c = lane + r * 64;
        out[(size_t)node * ldo + c] = f2b((vA[r] - m) * rsg * lng[c] + lnb[c]);
        out[(size_t)node * ldo + CH + c] = f2b((vB[r] - m) * rsg * lng[CH + c] + lnb[CH + c]);
    }
}

__global__ void k_const4(const float* __restrict__ pooled, const float* __restrict__ ow,
                         const float* __restrict__ ob, float* __restrict__ c4, float invn) {
    int j = threadIdx.x >> 6, lane = threadIdx.x & 63;
    float s = 0.f;
    for (int c = lane; c < 256; c += 64) s += pooled[c] * invn * ow[j * 320 + c];
#pragma unroll
    for (int off = 32; off > 0; off >>= 1) s += __shfl_down(s, off);
    if (lane == 0) c4[j] = s + ob[j];
}

__global__ void k_out(const unsigned short* __restrict__ hcat, const float* __restrict__ ow,
                      const float* __restrict__ c4, float* __restrict__ out, int n) {
    int t = blockIdx.x * 256 + threadIdx.x;
    int node = t >> 2, j = t & 3;
    if (node >= n) return;
    const unsigned short* xg = hcat + (size_t)node * 320 + 256;
    const float* w = ow + j * 320 + 256;
    float s = c4[j];
#pragma unroll
    for (int k = 0; k < 64; ++k) s = fmaf(b2f(xg[k]), w[k], s);
    out[(size_t)node * 4 + j] = s;
}

// ---------------- MFMA bf16 GEMM ----------------
enum { MF_BIAS = 1, MF_LRELU = 2, MF_DINV = 4, MF_STOREF = 8, MF_STOREB = 16,
       MF_STATS = 32, MF_COLSUM = 64 };

template <int BN, int MODE>
__launch_bounds__(256)
__global__ void k_mgemm(const unsigned short* __restrict__ A, int lda, int K,
                        const unsigned short* __restrict__ W,  // [C][K]
                        const float* __restrict__ bias,
                        float* __restrict__ OutF, unsigned short* __restrict__ OutB, int ldo,
                        const float* __restrict__ dinv,
                        float* __restrict__ sum_o, float* __restrict__ ss_o,
                        unsigned* __restrict__ maxk_o) {
    constexpr int BM = 128;
    constexpr int LDT = 40;  // ushort stride per 32-k row: 2-way bank alias (free)
    __shared__ unsigned short As[BM * LDT];
    __shared__ unsigned short Ws[BN * LDT];
    __shared__ float redS[2 * 128];
    __shared__ unsigned redM[128];

    const int tid = threadIdx.x;
    const int wid = tid >> 6, lane = tid & 63;
    const int quad = lane >> 4, lrow = lane & 15;
    const int bn0 = blockIdx.x * BM;
    const int bc0 = blockIdx.y * BN;

    constexpr int NI = (BN == 128) ? 4 : 2;
    constexpr int NJ = 4;
    const int wm = (BN == 128) ? (wid & 1) * 64 : wid * 32;
    const int wn = (BN == 128) ? (wid >> 1) * 64 : 0;

    if (MODE & (MF_STATS | MF_COLSUM)) {
        for (int c = tid; c < BN; c += 256) {
            redS[c] = 0.f; redS[128 + c] = 0.f; redM[c] = 0u;
        }
    }

    f32x4 acc[NI][NJ] = {};

    for (int k0 = 0; k0 < K; k0 += 32) {
#pragma unroll
        for (int h = 0; h < 2; ++h) {
            int ch = tid + h * 256;
            int row = ch >> 2, cp = ch & 3;
            const unsigned short* src = A + (size_t)(bn0 + row) * lda + k0 + cp * 8;
            *(float4*)&As[row * LDT + cp * 8] = *(const float4*)src;
        }
#pragma unroll
        for (int h = 0; h < BN / 64; ++h) {
            int ch = tid + h * 256;
            int row = ch >> 2, cp = ch & 3;
            const unsigned short* src = W + (size_t)(bc0 + row) * K + k0 + cp * 8;
            *(float4*)&Ws[row * LDT + cp * 8] = *(const float4*)src;
        }
        __syncthreads();
        frag8 af[NI], bf[NJ];
#pragma unroll
        for (int i = 0; i < NI; ++i)
            af[i] = *(const frag8*)&As[(wm + i * 16 + lrow) * LDT + quad * 8];
#pragma unroll
        for (int j = 0; j < NJ; ++j)
            bf[j] = *(const frag8*)&Ws[(wn + j * 16 + lrow) * LDT + quad * 8];
#pragma unroll
        for (int i = 0; i < NI; ++i)
#pragma unroll
            for (int j = 0; j < NJ; ++j)
                acc[i][j] = __builtin_amdgcn_mfma_f32_16x16x32_bf16(af[i], bf[j], acc[i][j], 0, 0, 0);
        __syncthreads();
    }

    // epilogue: C/D layout col=lane&15, row=quad*4+reg
#pragma unroll
    for (int j = 0; j < NJ; ++j) {
        const int col = bc0 + wn + j * 16 + lrow;
        float bv = (MODE & MF_BIAS) ? bias[col] : 0.f;
        float s = 0.f, q = 0.f, m = -3.4e38f;
#pragma unroll
        for (int i = 0; i < NI; ++i) {
            const int rowb = bn0 + wm + i * 16 + quad * 4;
#pragma unroll
            for (int r = 0; r < 4; ++r) {
                float t = acc[i][j][r] + bv;
                if (MODE & MF_LRELU) t = lrelu01(t);
                if (MODE & MF_DINV) t *= dinv[rowb + r];
                if (MODE & MF_STOREF) OutF[(size_t)(rowb + r) * ldo + col] = t;
                if (MODE & MF_STOREB) OutB[(size_t)(rowb + r) * ldo + col] = f2b(t);
                s += t; q += t * t; m = fmaxf(m, t);
            }
        }
        if (MODE & (MF_STATS | MF_COLSUM)) {
            s += __shfl_xor(s, 16); s += __shfl_xor(s, 32);
            if (MODE & MF_STATS) {
                q += __shfl_xor(q, 16); q += __shfl_xor(q, 32);
                m = fmaxf(m, __shfl_xor(m, 16)); m = fmaxf(m, __shfl_xor(m, 32));
            }
            if (quad == 0) {
                int lc = wn + j * 16 + lrow;
                atomicAdd(&redS[lc], s);
                if (MODE & MF_STATS) {
                    atomicAdd(&redS[128 + lc], q);
                    atomicMax(&redM[lc], fkey(m));
                }
            }
        }
    }
    if (MODE & (MF_STATS | MF_COLSUM)) {
        __syncthreads();
        for (int c = tid; c < BN; c += 256) {
            atomAddF(&sum_o[bc0 + c], redS[c]);
            if (MODE & MF_STATS) {
                atomAddF(&ss_o[bc0 + c], redS[128 + c]);
                atomicMax(&maxk_o[bc0 + c], redM[c]);
            }
        }
    }
}

// ---------------- launch ----------------
// Buffer lifetimes (all aliasing verified against stream order):
//   F1 [N,128]f32: z2 -> agg1 (first N*64) -> agg2
//   B1 [N,64] u16: h1 -> nf1
//   B2 [N,128]u16: A3 -> q1 (first N*64) -> hln1 -> nf2
//   B3 [N,128]u16: hmid -> q2
//   H  [N,320]u16: xg cols 256.. (early), LN2 out cols 0..255 (late)

extern "C" void kernel_launch(void* const* d_in, const int* in_sizes, int n_in,
                              void* d_out, int out_size, void* d_ws, size_t ws_size,
                              hipStream_t stream) {
    const float* x   = (const float*)d_in[0];
    const int*   ei  = (const int*)d_in[1];
    const float* c1w = (const float*)d_in[2];  const float* c1b = (const float*)d_in[3];
    const float* c2w = (const float*)d_in[4];  const float* c2b = (const float*)d_in[5];
    const float* c3w = (const float*)d_in[6];  const float* c3b = (const float*)d_in[7];
    const float* f1w = (const float*)d_in[8];  const float* f1b = (const float*)d_in[9];
    const float* f2w = (const float*)d_in[10]; const float* f2b = (const float*)d_in[11];
    const float* f3w = (const float*)d_in[12]; const float* f3b = (const float*)d_in[13];
    const float* cv1w = (const float*)d_in[14]; const float* cv1b = (const float*)d_in[15];
    const float* li1w = (const float*)d_in[16]; const float* li1b = (const float*)d_in[17];
    const float* gc1w = (const float*)d_in[18]; const float* gc1b = (const float*)d_in[19];
    const float* ln1g = (const float*)d_in[20]; const float* ln1b = (const float*)d_in[21];
    const float* cv2w = (const float*)d_in[22]; const float* cv2b = (const float*)d_in[23];
    const float* li2w = (const float*)d_in[24]; const float* li2b = (const float*)d_in[25];
    const float* gc2w = (const float*)d_in[26]; const float* gc2b = (const float*)d_in[27];
    const float* ln2g = (const float*)d_in[28]; const float* ln2b = (const float*)d_in[29];
    const float* cv3w = (const float*)d_in[30]; const float* cv3b = (const float*)d_in[31];
    const float* ow  = (const float*)d_in[32]; const float* ob  = (const float*)d_in[33];
    float* out = (float*)d_out;

    const int N = in_sizes[0] / 3;
    const int E = in_sizes[1] / 2;
    const int* srcI = ei;
    const int* dstI = ei + E;

    char* base = (char*)d_ws;
    size_t off = 0;
    auto take = [&](size_t bytes) -> char* {
        char* p = base + off;
        off = (off + bytes + 255) & ~(size_t)255;
        return p;
    };
    int*   deg    = (int*)  take((size_t)N * 4);
    float* dinv   = (float*)take((size_t)N * 4);
    int*   startv = (int*)  take((size_t)N * 4);
    int*   cursor = (int*)  take((size_t)N * 4);
    int*   csr    = (int*)  take((size_t)E * 4);
    int*   bsum   = (int*)  take(512 * 4);
    float* sm     = (float*)take(8192 * 4);
    unsigned short* WB = (unsigned short*)take(278528 * 2);
    unsigned short* H  = (unsigned short*)take((size_t)N * 320 * 2);
    float* F1 = (float*)take((size_t)N * 128 * 4);
    unsigned short* B1 = (unsigned short*)take((size_t)N * 64 * 2);
    unsigned short* B2 = (unsigned short*)take((size_t)N * 128 * 2);
    unsigned short* B3 = (unsigned short*)take((size_t)N * 128 * 2);

    // bf16 weights inside WB
    unsigned short* c2wb  = WB + 0;
    unsigned short* c3wb  = WB + 8192;
    unsigned short* li1wb = WB + 139264;
    unsigned short* gc1wb = WB + 143360;
    unsigned short* cv2wb = WB + 147456;
    unsigned short* li2wb = WB + 163840;
    unsigned short* gc2wb = WB + 180224;
    unsigned short* cv3wb = WB + 196608;

    // sm layout (floats): [0,3712) zeroed
    float* sum2 = sm + 0;    float* ss2 = sm + 128;
    float* sum3 = sm + 256;  float* ss3 = sm + 1280;
    unsigned* maxk = (unsigned*)(sm + 2304);   // 1024
    float* pooled = sm + 3328;                 // 256
    unsigned* dmax = (unsigned*)(sm + 3584);   // 128 dummy max for z2 stats
    float* mu2 = sm + 3712; float* rs2 = sm + 3840;
    float* T9  = sm + 3968; float* c4 = sm + 3984;
    float* gbuf = sm + 4096;  // 1024
    float* a1   = sm + 5120;  // 512

    const float invn = 1.0f / (float)N;
    const dim3 blk(256);
    const unsigned GX = (unsigned)(N / 128);   // 625
    const unsigned NB = cdivu((unsigned)N, 256);  // 313 scan blocks (<=512)

    hipMemsetAsync(deg, 0, (size_t)N * 4, stream);
    hipMemsetAsync(sm, 0, 3712 * 4, stream);

    // ---- graph prep: deg, dinv, CSR ----
    k_deg<<<cdivu(E, 256), blk, 0, stream>>>(dstI, deg, E);
    k_dinv<<<cdivu(N, 256), blk, 0, stream>>>(deg, dinv, N);
    k_scan_local<<<NB, blk, 0, stream>>>(deg, startv, bsum, N);
    k_scan_bsum<<<1, 512, 0, stream>>>(bsum, (int)NB);
    k_scan_add<<<NB, blk, 0, stream>>>(startv, bsum, cursor, N);
    k_fill<<<cdivu(E, 256), blk, 0, stream>>>(srcI, dstI, cursor, csr, E);

    k_wconv<<<cdivu(278528, 256), blk, 0, stream>>>(c2w, c3w, li1w, gc1w, cv2w, li2w, gc2w, cv3w, WB);

    // ---- TNet ----
    k_h1<<<cdivu((unsigned)N * 64, 256), blk, 0, stream>>>(x, c1w, c1b, B1, N);
    k_mgemm<128, (MF_BIAS | MF_STOREF | MF_STATS)><<<dim3(GX, 1), blk, 0, stream>>>(
        B1, 64, 64, c2wb, c2b, F1, nullptr, 128, nullptr, sum2, ss2, dmax);
    k_murs<<<1, 128, 0, stream>>>(sum2, ss2, mu2, rs2, invn);
    k_prebn<<<cdivu((unsigned)N * 128 / 4, 256), blk, 0, stream>>>(F1, mu2, rs2, B2, N * 128);
    k_mgemm<128, (MF_BIAS | MF_STATS)><<<dim3(GX, 8), blk, 0, stream>>>(
        B2, 128, 128, c3wb, c3b, nullptr, nullptr, 0, nullptr, sum3, ss3, maxk);
    k_g<<<4, blk, 0, stream>>>(sum3, ss3, maxk, gbuf, invn);
    k_fc1<<<8, blk, 0, stream>>>(gbuf, f1w, f1b, a1);
    k_fc23<<<1, blk, 0, stream>>>(a1, f2w, f2b, f3w, f3b, T9);
    k_xg<<<cdivu((unsigned)N * 64, 256), blk, 0, stream>>>(x, T9, cv1w, cv1b, H + 256, N);

    // ---- GCN block 1 (C=64) ----
    k_mgemm<64, (MF_BIAS | MF_LRELU | MF_STOREB)><<<dim3(GX, 1), blk, 0, stream>>>(
        H + 256, 320, 64, li1wb, li1b, nullptr, B1, 64, nullptr, nullptr, nullptr, nullptr);
    k_mgemm<64, (MF_DINV | MF_STOREB)><<<dim3(GX, 1), blk, 0, stream>>>(
        B1, 64, 64, gc1wb, nullptr, nullptr, B2, 64, dinv, nullptr, nullptr, nullptr);
    k_gather<64><<<cdivu((unsigned)N, 4), blk, 0, stream>>>(startv, deg, csr, B2, F1, N);
    k_ln<64><<<cdivu(N, 4), blk, 0, stream>>>(B1, F1, dinv, gc1b, ln1g, ln1b, B2, 128, N);
    k_mgemm<128, (MF_BIAS | MF_LRELU | MF_STOREB)><<<dim3(GX, 1), blk, 0, stream>>>(
        B2, 128, 128, cv2wb, cv2b, nullptr, B3, 128, nullptr, nullptr, nullptr, nullptr);

    // ---- GCN block 2 (C=128) ----
    k_mgemm<128, (MF_BIAS | MF_LRELU | MF_STOREB)><<<dim3(GX, 1), blk, 0, stream>>>(
        B3, 128, 128, li2wb, li2b, nullptr, B2, 128, nullptr, nullptr, nullptr, nullptr);
    k_mgemm<128, (MF_DINV | MF_STOREB)><<<dim3(GX, 1), blk, 0, stream>>>(
        B2, 128, 128, gc2wb, nullptr, nullptr, B3, 128, dinv, nullptr, nullptr, nullptr);
    k_gather<128><<<cdivu((unsigned)N, 4), blk, 0, stream>>>(startv, deg, csr, B3, F1, N);
    k_ln<128><<<cdivu(N, 4), blk, 0, stream>>>(B2, F1, dinv, gc2b, ln2g, ln2b, H, 320, N);

    // ---- conv3 (K=320 -> 256) fused column-sum only ----
    k_mgemm<128, (MF_BIAS | MF_LRELU | MF_COLSUM)><<<dim3(GX, 2), blk, 0, stream>>>(
        H, 320, 320, cv3wb, cv3b, nullptr, nullptr, 0, nullptr, pooled, nullptr, nullptr);

    // ---- head ----
    k_const4<<<1, 256, 0, stream>>>(pooled, ow, ob, c4, invn);
    k_out<<<cdivu((unsigned)N * 4, 256), blk, 0, stream>>>(H, ow, c4, out, N);
}

// Round 5
// 676.062 us; speedup vs baseline: 5.5324x; 1.2354x over previous
//
#include <hip/hip_runtime.h>
#include <cstddef>

#define EPSV 1e-5f

typedef __attribute__((ext_vector_type(8))) short frag8;   // 8 bf16 (4 VGPRs)
typedef __attribute__((ext_vector_type(4))) float f32x4;   // MFMA acc

__device__ __forceinline__ float lrelu01(float v) { return v > 0.f ? v : 0.01f * v; }
__device__ __forceinline__ void atomAddF(float* p, float v) { unsafeAtomicAdd(p, v); }
__device__ __forceinline__ unsigned fkey(float f) {
    unsigned u = __float_as_uint(f);
    return (u & 0x80000000u) ? ~u : (u | 0x80000000u);
}
__device__ __forceinline__ unsigned short f2b(float f) {  // RNE float->bf16
    unsigned u = __float_as_uint(f);
    unsigned r = u + 0x7fffu + ((u >> 16) & 1u);
    return (unsigned short)(r >> 16);
}
__device__ __forceinline__ float b2f(unsigned short h) {
    return __uint_as_float(((unsigned)h) << 16);
}

static inline unsigned cdivu(unsigned a, unsigned b) { return (a + b - 1) / b; }

// ---------------- graph prep: degree, dinv, CSR build ----------------

__global__ void k_deg(const int* __restrict__ dst, int* __restrict__ deg, int E) {
    int e = blockIdx.x * 256 + threadIdx.x;
    if (e < E) atomicAdd(&deg[dst[e]], 1);
}

__global__ void k_dinv(const int* __restrict__ deg, float* __restrict__ dinv, int n) {
    int i = blockIdx.x * 256 + threadIdx.x;
    if (i < n) dinv[i] = rsqrtf((float)(deg[i] + 1));  // +1 self loop
}

// per-block exclusive scan of deg -> startv (local), block sums -> bsum
__global__ void k_scan_local(const int* __restrict__ deg, int* __restrict__ startv,
                             int* __restrict__ bsum, int n) {
    __shared__ int t0[256];
    int tid = threadIdx.x;
    int i = blockIdx.x * 256 + tid;
    int v = (i < n) ? deg[i] : 0;
    t0[tid] = v;
    __syncthreads();
    for (int o = 1; o < 256; o <<= 1) {
        int add = (tid >= o) ? t0[tid - o] : 0;
        __syncthreads();
        t0[tid] += add;
        __syncthreads();
    }
    if (i < n) startv[i] = t0[tid] - v;
    if (tid == 255) bsum[blockIdx.x] = t0[255];
}

// single block of 512: exclusive scan of bsum[nb] in place (nb <= 512)
__global__ void k_scan_bsum(int* __restrict__ bsum, int nb) {
    __shared__ int t0[512];
    int tid = threadIdx.x;
    int v = (tid < nb) ? bsum[tid] : 0;
    t0[tid] = v;
    __syncthreads();
    for (int o = 1; o < 512; o <<= 1) {
        int add = (tid >= o) ? t0[tid - o] : 0;
        __syncthreads();
        t0[tid] += add;
        __syncthreads();
    }
    if (tid < nb) bsum[tid] = t0[tid] - v;
}

__global__ void k_scan_add(int* __restrict__ startv, const int* __restrict__ bsum,
                           int* __restrict__ cursor, int n) {
    int i = blockIdx.x * 256 + threadIdx.x;
    if (i < n) {
        int s = startv[i] + bsum[blockIdx.x];
        startv[i] = s;
        cursor[i] = s;
    }
}

__global__ void k_fill(const int* __restrict__ src, const int* __restrict__ dst,
                       int* __restrict__ cursor, int* __restrict__ csr, int E) {
    int e = blockIdx.x * 256 + threadIdx.x;
    if (e < E) {
        int pos = atomicAdd(&cursor[dst[e]], 1);
        csr[pos] = src[e];
    }
}

// ---------------- fused gather + LN ----------------
// agg[d] = q[d] + sum_{s in neigh(d)} q[s]  (in registers, never stored)
// b = lrelu(dinv[d]*agg + gcn_b); out = LN(concat[nf, b]) * g + beta  (bf16)
// wave per node; 8 independent q-row loads in flight (latency hiding).
template <int CH>
__launch_bounds__(256)
__global__ void k_gln(const int* __restrict__ startv, const int* __restrict__ degv,
                      const int* __restrict__ csr, const unsigned short* __restrict__ q,
                      const unsigned short* __restrict__ nf, const float* __restrict__ dinv,
                      const float* __restrict__ gcn_b, const float* __restrict__ lng,
                      const float* __restrict__ lnb, unsigned short* __restrict__ outp,
                      int ldo, int n) {
    int wv = threadIdx.x >> 6, lane = threadIdx.x & 63;
    int node = blockIdx.x * 4 + wv;
    if (node >= n) return;
    constexpr int V = CH / 64;  // channels per lane (1 or 2)
    float a0, a1 = 0.f;
    {
        const unsigned short* qrow = q + (size_t)node * CH;
        if (V == 1) {
            a0 = b2f(qrow[lane]);
        } else {
            unsigned u = *(const unsigned*)(qrow + lane * 2);
            a0 = __uint_as_float((u & 0xffffu) << 16);
            a1 = __uint_as_float(u & 0xffff0000u);
        }
    }
    int s0 = startv[node], cnt = degv[node];
    for (int c0 = 0; c0 < cnt; c0 += 64) {
        int m = cnt - c0; if (m > 64) m = 64;
        int idx = (lane < m) ? csr[s0 + c0 + lane] : 0;
        int j = 0;
        for (; j + 8 <= m; j += 8) {
            unsigned uu[8];
#pragma unroll
            for (int t = 0; t < 8; ++t) {
                int s = __shfl(idx, j + t);
                if (V == 1) uu[t] = q[(size_t)s * CH + lane];
                else uu[t] = *(const unsigned*)(q + (size_t)s * CH + lane * 2);
            }
#pragma unroll
            for (int t = 0; t < 8; ++t) {
                if (V == 1) {
                    a0 += __uint_as_float(uu[t] << 16);
                } else {
                    a0 += __uint_as_float((uu[t] & 0xffffu) << 16);
                    a1 += __uint_as_float(uu[t] & 0xffff0000u);
                }
            }
        }
        for (; j < m; ++j) {
            int s = __shfl(idx, j);
            if (V == 1) {
                a0 += b2f(q[(size_t)s * CH + lane]);
            } else {
                unsigned u = *(const unsigned*)(q + (size_t)s * CH + lane * 2);
                a0 += __uint_as_float((u & 0xffffu) << 16);
                a1 += __uint_as_float(u & 0xffff0000u);
            }
        }
    }
    // GCN epilogue + LN
    float di = dinv[node];
    float b0, b1 = 0.f, n0, n1 = 0.f;
    {
        const unsigned short* nrow = nf + (size_t)node * CH;
        if (V == 1) {
            b0 = lrelu01(di * a0 + gcn_b[lane]);
            n0 = b2f(nrow[lane]);
        } else {
            int c = lane * 2;
            b0 = lrelu01(di * a0 + gcn_b[c]);
            b1 = lrelu01(di * a1 + gcn_b[c + 1]);
            unsigned u = *(const unsigned*)(nrow + c);
            n0 = __uint_as_float((u & 0xffffu) << 16);
            n1 = __uint_as_float(u & 0xffff0000u);
        }
    }
    float s = n0 + b0 + n1 + b1;
    float ss = n0 * n0 + b0 * b0 + n1 * n1 + b1 * b1;
#pragma unroll
    for (int off = 32; off > 0; off >>= 1) {
        s += __shfl_xor(s, off);
        ss += __shfl_xor(ss, off);
    }
    const float inv2c = 1.f / (float)(2 * CH);
    float mu = s * inv2c;
    float var = ss * inv2c - mu * mu;
    float rsg = rsqrtf(var + EPSV);
    unsigned short* orow = outp + (size_t)node * ldo;
    if (V == 1) {
        orow[lane] = f2b((n0 - mu) * rsg * lng[lane] + lnb[lane]);
        orow[64 + lane] = f2b((b0 - mu) * rsg * lng[64 + lane] + lnb[64 + lane]);
    } else {
        int c = lane * 2;
        ushort2 oA, oB;
        oA.x = f2b((n0 - mu) * rsg * lng[c] + lnb[c]);
        oA.y = f2b((n1 - mu) * rsg * lng[c + 1] + lnb[c + 1]);
        oB.x = f2b((b0 - mu) * rsg * lng[CH + c] + lnb[CH + c]);
        oB.y = f2b((b1 - mu) * rsg * lng[CH + c + 1] + lnb[CH + c + 1]);
        *(ushort2*)(orow + c) = oA;
        *(ushort2*)(orow + CH + c) = oB;
    }
}

// ---------------- small kernels ----------------

// convert all 8 GEMM weight matrices fp32 -> bf16 into one packed region
__global__ void k_wconv(const float* __restrict__ s0, const float* __restrict__ s1,
                        const float* __restrict__ s2, const float* __restrict__ s3,
                        const float* __restrict__ s4, const float* __restrict__ s5,
                        const float* __restrict__ s6, const float* __restrict__ s7,
                        unsigned short* __restrict__ dst) {
    int t = blockIdx.x * 256 + threadIdx.x;
    if (t >= 278528) return;
    const float* srcs[8] = {s0, s1, s2, s3, s4, s5, s6, s7};
    const int off[9] = {0, 8192, 139264, 143360, 147456, 163840, 180224, 196608, 278528};
    int seg = 0;
    while (t >= off[seg + 1]) ++seg;
    dst[t] = f2b(srcs[seg][t - off[seg]]);
}

// h1 = relu(x @ c1w.T + c1b) -> bf16 [N,64]
__global__ void k_h1(const float* __restrict__ x, const float* __restrict__ w,
                     const float* __restrict__ b, unsigned short* __restrict__ h1, int n) {
    int t = blockIdx.x * 256 + threadIdx.x;
    int node = t >> 6, c = t & 63;
    if (node >= n) return;
    float x0 = x[node * 3], x1 = x[node * 3 + 1], x2 = x[node * 3 + 2];
    float v = x0 * w[c * 3] + x1 * w[c * 3 + 1] + x2 * w[c * 3 + 2] + b[c];
    h1[(size_t)node * 64 + c] = f2b(fmaxf(v, 0.f));
}

__global__ void k_murs(const float* __restrict__ sum2, const float* __restrict__ ss2,
                       float* __restrict__ mu2, float* __restrict__ rs2, float invn) {
    int c = threadIdx.x;  // 128
    float m = sum2[c] * invn;
    float var = ss2[c] * invn - m * m;
    mu2[c] = m;
    rs2[c] = rsqrtf(var + EPSV);
}

// A3 = bf16(relu((z2 - mu)*rs)), z2 fp32 [N,128]
__global__ void k_prebn(const float* __restrict__ z, const float* __restrict__ mu,
                        const float* __restrict__ rs, unsigned short* __restrict__ a3,
                        int total) {
    int t = (blockIdx.x * 256 + threadIdx.x) * 4;
    if (t >= total) return;
    int c = t & 127;
    float4 v = *(const float4*)(z + t);
    ushort4 o;
    o.x = f2b(fmaxf((v.x - mu[c + 0]) * rs[c + 0], 0.f));
    o.y = f2b(fmaxf((v.y - mu[c + 1]) * rs[c + 1], 0.f));
    o.z = f2b(fmaxf((v.z - mu[c + 2]) * rs[c + 2], 0.f));
    o.w = f2b(fmaxf((v.w - mu[c + 3]) * rs[c + 3], 0.f));
    *(ushort4*)(a3 + t) = o;
}

// g[c] = relu((max_c - mu_c) * rsqrt(var_c + eps)), c in [0,1024)
__global__ void k_g(const float* __restrict__ sum3, const float* __restrict__ ss3,
                    const unsigned* __restrict__ maxk, float* __restrict__ g, float invn) {
    int c = blockIdx.x * 256 + threadIdx.x;
    float m = sum3[c] * invn;
    float var = ss3[c] * invn - m * m;
    unsigned k = maxk[c];
    unsigned u = (k & 0x80000000u) ? (k & 0x7FFFFFFFu) : ~k;
    g[c] = fmaxf((__uint_as_float(u) - m) * rsqrtf(var + EPSV), 0.f);
}

// fc1: a1[row] = relu(f1w[row,:] @ g + f1b[row]); grid 8 x 256, 4 threads/row
__global__ void k_fc1(const float* __restrict__ g, const float* __restrict__ f1w,
                      const float* __restrict__ f1b, float* __restrict__ a1) {
    int row = blockIdx.x * 64 + (threadIdx.x >> 2);
    int part = threadIdx.x & 3;
    const float* w = f1w + (size_t)row * 1024 + part * 256;
    const float* gg = g + part * 256;
    float s = 0.f;
    for (int k = 0; k < 256; ++k) s = fmaf(w[k], gg[k], s);
    s += __shfl_xor(s, 1); s += __shfl_xor(s, 2);
    if (part == 0) a1[row] = fmaxf(s + f1b[row], 0.f);
}

__launch_bounds__(256)
__global__ void k_fc23(const float* __restrict__ a1, const float* __restrict__ f2w,
                       const float* __restrict__ f2b, const float* __restrict__ f3w,
                       const float* __restrict__ f3b, float* __restrict__ T9) {
    __shared__ float a2[256];
    int tid = threadIdx.x;
    {
        const float* w = f2w + (size_t)tid * 512;
        float s = f2b[tid];
        for (int k = 0; k < 512; ++k) s = fmaf(w[k], a1[k], s);
        a2[tid] = fmaxf(s, 0.f);
    }
    __syncthreads();
    if (tid < 9) {
        const float* w = f3w + (size_t)tid * 256;
        float s = f3b[tid];
        for (int k = 0; k < 256; ++k) s = fmaf(w[k], a2[k], s);
        if (tid == 0 || tid == 4 || tid == 8) s += 1.f;
        T9[tid] = s;
    }
}

// xg = lrelu((x@T) @ conv1w.T + b) -> bf16 into hcat cols 256.. (ushort stride 320)
__global__ void k_xg(const float* __restrict__ x, const float* __restrict__ T9,
                     const float* __restrict__ w, const float* __restrict__ b,
                     unsigned short* __restrict__ xg, int n) {
    int t = blockIdx.x * 256 + threadIdx.x;
    int node = t >> 6, c = t & 63;
    if (node >= n) return;
    float x0 = x[node * 3], x1 = x[node * 3 + 1], x2 = x[node * 3 + 2];
    float h0 = x0 * T9[0] + x1 * T9[3] + x2 * T9[6];
    float h1 = x0 * T9[1] + x1 * T9[4] + x2 * T9[7];
    float h2 = x0 * T9[2] + x1 * T9[5] + x2 * T9[8];
    float v = h0 * w[c * 3] + h1 * w[c * 3 + 1] + h2 * w[c * 3 + 2] + b[c];
    xg[(size_t)node * 320 + c] = f2b(lrelu01(v));
}

__global__ void k_const4(const float* __restrict__ pooled, const float* __restrict__ ow,
                         const float* __restrict__ ob, float* __restrict__ c4, float invn) {
    int j = threadIdx.x >> 6, lane = threadIdx.x & 63;
    float s = 0.f;
    for (int c = lane; c < 256; c += 64) s += pooled[c] * invn * ow[j * 320 + c];
#pragma unroll
    for (int off = 32; off > 0; off >>= 1) s += __shfl_down(s, off);
    if (lane == 0) c4[j] = s + ob[j];
}

__global__ void k_out(const unsigned short* __restrict__ hcat, const float* __restrict__ ow,
                      const float* __restrict__ c4, float* __restrict__ out, int n) {
    int t = blockIdx.x * 256 + threadIdx.x;
    int node = t >> 2, j = t & 3;
    if (node >= n) return;
    const unsigned short* xg = hcat + (size_t)node * 320 + 256;
    const float* w = ow + j * 320 + 256;
    float s = c4[j];
#pragma unroll
    for (int k = 0; k < 64; ++k) s = fmaf(b2f(xg[k]), w[k], s);
    out[(size_t)node * 4 + j] = s;
}

// ---------------- MFMA bf16 GEMM ----------------
enum { MF_BIAS = 1, MF_LRELU = 2, MF_DINV = 4, MF_STOREF = 8, MF_STOREB = 16,
       MF_STATS = 32, MF_COLSUM = 64 };

template <int BN, int MODE>
__launch_bounds__(256)
__global__ void k_mgemm(const unsigned short* __restrict__ A, int lda, int K,
                        const unsigned short* __restrict__ W,  // [C][K]
                        const float* __restrict__ bias,
                        float* __restrict__ OutF, unsigned short* __restrict__ OutB, int ldo,
                        const float* __restrict__ dinv,
                        float* __restrict__ sum_o, float* __restrict__ ss_o,
                        unsigned* __restrict__ maxk_o) {
    constexpr int BM = 128;
    constexpr int LDT = 40;  // ushort stride per 32-k row: 2-way bank alias (free)
    __shared__ unsigned short As[BM * LDT];
    __shared__ unsigned short Ws[BN * LDT];
    __shared__ float redS[2 * 128];
    __shared__ unsigned redM[128];

    const int tid = threadIdx.x;
    const int wid = tid >> 6, lane = tid & 63;
    const int quad = lane >> 4, lrow = lane & 15;
    const int bn0 = blockIdx.x * BM;
    const int bc0 = blockIdx.y * BN;

    constexpr int NI = (BN == 128) ? 4 : 2;
    constexpr int NJ = 4;
    const int wm = (BN == 128) ? (wid & 1) * 64 : wid * 32;
    const int wn = (BN == 128) ? (wid >> 1) * 64 : 0;

    if (MODE & (MF_STATS | MF_COLSUM)) {
        for (int c = tid; c < BN; c += 256) {
            redS[c] = 0.f; redS[128 + c] = 0.f; redM[c] = 0u;
        }
    }

    f32x4 acc[NI][NJ] = {};

    for (int k0 = 0; k0 < K; k0 += 32) {
#pragma unroll
        for (int h = 0; h < 2; ++h) {
            int ch = tid + h * 256;
            int row = ch >> 2, cp = ch & 3;
            const unsigned short* src = A + (size_t)(bn0 + row) * lda + k0 + cp * 8;
            *(float4*)&As[row * LDT + cp * 8] = *(const float4*)src;
        }
#pragma unroll
        for (int h = 0; h < BN / 64; ++h) {
            int ch = tid + h * 256;
            int row = ch >> 2, cp = ch & 3;
            const unsigned short* src = W + (size_t)(bc0 + row) * K + k0 + cp * 8;
            *(float4*)&Ws[row * LDT + cp * 8] = *(const float4*)src;
        }
        __syncthreads();
        frag8 af[NI], bf[NJ];
#pragma unroll
        for (int i = 0; i < NI; ++i)
            af[i] = *(const frag8*)&As[(wm + i * 16 + lrow) * LDT + quad * 8];
#pragma unroll
        for (int j = 0; j < NJ; ++j)
            bf[j] = *(const frag8*)&Ws[(wn + j * 16 + lrow) * LDT + quad * 8];
#pragma unroll
        for (int i = 0; i < NI; ++i)
#pragma unroll
            for (int j = 0; j < NJ; ++j)
                acc[i][j] = __builtin_amdgcn_mfma_f32_16x16x32_bf16(af[i], bf[j], acc[i][j], 0, 0, 0);
        __syncthreads();
    }

    // epilogue: C/D layout col=lane&15, row=quad*4+reg
#pragma unroll
    for (int j = 0; j < NJ; ++j) {
        const int col = bc0 + wn + j * 16 + lrow;
        float bv = (MODE & MF_BIAS) ? bias[col] : 0.f;
        float s = 0.f, q = 0.f, m = -3.4e38f;
#pragma unroll
        for (int i = 0; i < NI; ++i) {
            const int rowb = bn0 + wm + i * 16 + quad * 4;
#pragma unroll
            for (int r = 0; r < 4; ++r) {
                float t = acc[i][j][r] + bv;
                if (MODE & MF_LRELU) t = lrelu01(t);
                if (MODE & MF_DINV) t *= dinv[rowb + r];
                if (MODE & MF_STOREF) OutF[(size_t)(rowb + r) * ldo + col] = t;
                if (MODE & MF_STOREB) OutB[(size_t)(rowb + r) * ldo + col] = f2b(t);
                s += t; q += t * t; m = fmaxf(m, t);
            }
        }
        if (MODE & (MF_STATS | MF_COLSUM)) {
            s += __shfl_xor(s, 16); s += __shfl_xor(s, 32);
            if (MODE & MF_STATS) {
                q += __shfl_xor(q, 16); q += __shfl_xor(q, 32);
                m = fmaxf(m, __shfl_xor(m, 16)); m = fmaxf(m, __shfl_xor(m, 32));
            }
            if (quad == 0) {
                int lc = wn + j * 16 + lrow;
                atomicAdd(&redS[lc], s);
                if (MODE & MF_STATS) {
                    atomicAdd(&redS[128 + lc], q);
                    atomicMax(&redM[lc], fkey(m));
                }
            }
        }
    }
    if (MODE & (MF_STATS | MF_COLSUM)) {
        __syncthreads();
        for (int c = tid; c < BN; c += 256) {
            atomAddF(&sum_o[bc0 + c], redS[c]);
            if (MODE & MF_STATS) {
                atomAddF(&ss_o[bc0 + c], redS[128 + c]);
                atomicMax(&maxk_o[bc0 + c], redM[c]);
            }
        }
    }
}

// ---------------- launch ----------------
// Buffer lifetimes (stream-order audited):
//   F1 [N,128]f32: z2 only
//   B1 [N,64] u16: h1 -> nf1
//   B2 [N,128]u16: A3 -> q1 (first N*64) -> hmid -> q2
//   B3 [N,128]u16: hln1 -> nf2
//   H  [N,320]u16: xg cols 256.. (early), LN2 out cols 0..255 (late)

extern "C" void kernel_launch(void* const* d_in, const int* in_sizes, int n_in,
                              void* d_out, int out_size, void* d_ws, size_t ws_size,
                              hipStream_t stream) {
    const float* x   = (const float*)d_in[0];
    const int*   ei  = (const int*)d_in[1];
    const float* c1w = (const float*)d_in[2];  const float* c1b = (const float*)d_in[3];
    const float* c2w = (const float*)d_in[4];  const float* c2b = (const float*)d_in[5];
    const float* c3w = (const float*)d_in[6];  const float* c3b = (const float*)d_in[7];
    const float* f1w = (const float*)d_in[8];  const float* f1b = (const float*)d_in[9];
    const float* f2w = (const float*)d_in[10]; const float* f2b = (const float*)d_in[11];
    const float* f3w = (const float*)d_in[12]; const float* f3b = (const float*)d_in[13];
    const float* cv1w = (const float*)d_in[14]; const float* cv1b = (const float*)d_in[15];
    const float* li1w = (const float*)d_in[16]; const float* li1b = (const float*)d_in[17];
    const float* gc1w = (const float*)d_in[18]; const float* gc1b = (const float*)d_in[19];
    const float* ln1g = (const float*)d_in[20]; const float* ln1b = (const float*)d_in[21];
    const float* cv2w = (const float*)d_in[22]; const float* cv2b = (const float*)d_in[23];
    const float* li2w = (const float*)d_in[24]; const float* li2b = (const float*)d_in[25];
    const float* gc2w = (const float*)d_in[26]; const float* gc2b = (const float*)d_in[27];
    const float* ln2g = (const float*)d_in[28]; const float* ln2b = (const float*)d_in[29];
    const float* cv3w = (const float*)d_in[30]; const float* cv3b = (const float*)d_in[31];
    const float* ow  = (const float*)d_in[32]; const float* ob  = (const float*)d_in[33];
    float* out = (float*)d_out;

    const int N = in_sizes[0] / 3;
    const int E = in_sizes[1] / 2;
    const int* srcI = ei;
    const int* dstI = ei + E;

    char* base = (char*)d_ws;
    size_t off = 0;
    auto take = [&](size_t bytes) -> char* {
        char* p = base + off;
        off = (off + bytes + 255) & ~(size_t)255;
        return p;
    };
    int*   deg    = (int*)  take((size_t)N * 4);
    float* dinv   = (float*)take((size_t)N * 4);
    int*   startv = (int*)  take((size_t)N * 4);
    int*   cursor = (int*)  take((size_t)N * 4);
    int*   csr    = (int*)  take((size_t)E * 4);
    int*   bsum   = (int*)  take(512 * 4);
    float* sm     = (float*)take(8192 * 4);
    unsigned short* WB = (unsigned short*)take(278528 * 2);
    unsigned short* H  = (unsigned short*)take((size_t)N * 320 * 2);
    float* F1 = (float*)take((size_t)N * 128 * 4);
    unsigned short* B1 = (unsigned short*)take((size_t)N * 64 * 2);
    unsigned short* B2 = (unsigned short*)take((size_t)N * 128 * 2);
    unsigned short* B3 = (unsigned short*)take((size_t)N * 128 * 2);

    // bf16 weights inside WB
    unsigned short* c2wb  = WB + 0;
    unsigned short* c3wb  = WB + 8192;
    unsigned short* li1wb = WB + 139264;
    unsigned short* gc1wb = WB + 143360;
    unsigned short* cv2wb = WB + 147456;
    unsigned short* li2wb = WB + 163840;
    unsigned short* gc2wb = WB + 180224;
    unsigned short* cv3wb = WB + 196608;

    // sm layout (floats): [0,3712) zeroed
    float* sum2 = sm + 0;    float* ss2 = sm + 128;
    float* sum3 = sm + 256;  float* ss3 = sm + 1280;
    unsigned* maxk = (unsigned*)(sm + 2304);   // 1024
    float* pooled = sm + 3328;                 // 256
    unsigned* dmax = (unsigned*)(sm + 3584);   // 128 dummy max for z2 stats
    float* mu2 = sm + 3712; float* rs2 = sm + 3840;
    float* T9  = sm + 3968; float* c4 = sm + 3984;
    float* gbuf = sm + 4096;  // 1024
    float* a1   = sm + 5120;  // 512

    const float invn = 1.0f / (float)N;
    const dim3 blk(256);
    const unsigned GX = (unsigned)(N / 128);      // 625
    const unsigned NB = cdivu((unsigned)N, 256);  // 313 scan blocks (<=512)

    hipMemsetAsync(deg, 0, (size_t)N * 4, stream);
    hipMemsetAsync(sm, 0, 3712 * 4, stream);

    // ---- graph prep: deg, dinv, CSR ----
    k_deg<<<cdivu(E, 256), blk, 0, stream>>>(dstI, deg, E);
    k_dinv<<<cdivu(N, 256), blk, 0, stream>>>(deg, dinv, N);
    k_scan_local<<<NB, blk, 0, stream>>>(deg, startv, bsum, N);
    k_scan_bsum<<<1, 512, 0, stream>>>(bsum, (int)NB);
    k_scan_add<<<NB, blk, 0, stream>>>(startv, bsum, cursor, N);
    k_fill<<<cdivu(E, 256), blk, 0, stream>>>(srcI, dstI, cursor, csr, E);

    k_wconv<<<cdivu(278528, 256), blk, 0, stream>>>(c2w, c3w, li1w, gc1w, cv2w, li2w, gc2w, cv3w, WB);

    // ---- TNet ----
    k_h1<<<cdivu((unsigned)N * 64, 256), blk, 0, stream>>>(x, c1w, c1b, B1, N);
    k_mgemm<128, (MF_BIAS | MF_STOREF | MF_STATS)><<<dim3(GX, 1), blk, 0, stream>>>(
        B1, 64, 64, c2wb, c2b, F1, nullptr, 128, nullptr, sum2, ss2, dmax);
    k_murs<<<1, 128, 0, stream>>>(sum2, ss2, mu2, rs2, invn);
    k_prebn<<<cdivu((unsigned)N * 128 / 4, 256), blk, 0, stream>>>(F1, mu2, rs2, B2, N * 128);
    k_mgemm<128, (MF_BIAS | MF_STATS)><<<dim3(GX, 8), blk, 0, stream>>>(
        B2, 128, 128, c3wb, c3b, nullptr, nullptr, 0, nullptr, sum3, ss3, maxk);
    k_g<<<4, blk, 0, stream>>>(sum3, ss3, maxk, gbuf, invn);
    k_fc1<<<8, blk, 0, stream>>>(gbuf, f1w, f1b, a1);
    k_fc23<<<1, blk, 0, stream>>>(a1, f2w, f2b, f3w, f3b, T9);
    k_xg<<<cdivu((unsigned)N * 64, 256), blk, 0, stream>>>(x, T9, cv1w, cv1b, H + 256, N);

    // ---- GCN block 1 (C=64) ----
    k_mgemm<64, (MF_BIAS | MF_LRELU | MF_STOREB)><<<dim3(GX, 1), blk, 0, stream>>>(
        H + 256, 320, 64, li1wb, li1b, nullptr, B1, 64, nullptr, nullptr, nullptr, nullptr);
    k_mgemm<64, (MF_DINV | MF_STOREB)><<<dim3(GX, 1), blk, 0, stream>>>(
        B1, 64, 64, gc1wb, nullptr, nullptr, B2, 64, dinv, nullptr, nullptr, nullptr);
    k_gln<64><<<cdivu((unsigned)N, 4), blk, 0, stream>>>(
        startv, deg, csr, B2, B1, dinv, gc1b, ln1g, ln1b, B3, 128, N);
    k_mgemm<128, (MF_BIAS | MF_LRELU | MF_STOREB)><<<dim3(GX, 1), blk, 0, stream>>>(
        B3, 128, 128, cv2wb, cv2b, nullptr, B2, 128, nullptr, nullptr, nullptr, nullptr);

    // ---- GCN block 2 (C=128) ----
    k_mgemm<128, (MF_BIAS | MF_LRELU | MF_STOREB)><<<dim3(GX, 1), blk, 0, stream>>>(
        B2, 128, 128, li2wb, li2b, nullptr, B3, 128, nullptr, nullptr, nullptr, nullptr);
    k_mgemm<128, (MF_DINV | MF_STOREB)><<<dim3(GX, 1), blk, 0, stream>>>(
        B3, 128, 128, gc2wb, nullptr, nullptr, B2, 128, dinv, nullptr, nullptr, nullptr);
    k_gln<128><<<cdivu((unsigned)N, 4), blk, 0, stream>>>(
        startv, deg, csr, B2, B3, dinv, gc2b, ln2g, ln2b, H, 320, N);

    // ---- conv3 (K=320 -> 256) fused column-sum only ----
    k_mgemm<128, (MF_BIAS | MF_LRELU | MF_COLSUM)><<<dim3(GX, 2), blk, 0, stream>>>(
        H, 320, 320, cv3wb, cv3b, nullptr, nullptr, 0, nullptr, pooled, nullptr, nullptr);

    // ---- head ----
    k_const4<<<1, 256, 0, stream>>>(pooled, ow, ob, c4, invn);
    k_out<<<cdivu((unsigned)N * 4, 256), blk, 0, stream>>>(H, ow, c4, out, N);
}

// Round 6
// 645.788 us; speedup vs baseline: 5.7918x; 1.0469x over previous
//
#include <hip/hip_runtime.h>
#include <cstddef>

#define EPSV 1e-5f

typedef __attribute__((ext_vector_type(8))) short frag8;   // 8 bf16 (4 VGPRs)
typedef __attribute__((ext_vector_type(4))) float f32x4;   // MFMA acc

__device__ __forceinline__ float lrelu01(float v) { return v > 0.f ? v : 0.01f * v; }
__device__ __forceinline__ void atomAddF(float* p, float v) { unsafeAtomicAdd(p, v); }
__device__ __forceinline__ unsigned fkey(float f) {
    unsigned u = __float_as_uint(f);
    return (u & 0x80000000u) ? ~u : (u | 0x80000000u);
}
__device__ __forceinline__ unsigned short f2b(float f) {  // RNE float->bf16
    unsigned u = __float_as_uint(f);
    unsigned r = u + 0x7fffu + ((u >> 16) & 1u);
    return (unsigned short)(r >> 16);
}
__device__ __forceinline__ float b2f(unsigned short h) {
    return __uint_as_float(((unsigned)h) << 16);
}

static inline unsigned cdivu(unsigned a, unsigned b) { return (a + b - 1) / b; }

// ---------------- graph prep: degree+rank, dinv, CSR build ----------------

// rank[e] = arrival index of edge e within its dst's list (atomic paid once here)
__global__ void k_degrank(const int* __restrict__ dst, int* __restrict__ deg,
                          int* __restrict__ rank, int E) {
    int e = blockIdx.x * 256 + threadIdx.x;
    if (e < E) rank[e] = atomicAdd(&deg[dst[e]], 1);
}

__global__ void k_dinv(const int* __restrict__ deg, float* __restrict__ dinv, int n) {
    int i = blockIdx.x * 256 + threadIdx.x;
    if (i < n) dinv[i] = rsqrtf((float)(deg[i] + 1));  // +1 self loop
}

// per-block exclusive scan of deg -> startv (local), block sums -> bsum
__global__ void k_scan_local(const int* __restrict__ deg, int* __restrict__ startv,
                             int* __restrict__ bsum, int n) {
    __shared__ int t0[256];
    int tid = threadIdx.x;
    int i = blockIdx.x * 256 + tid;
    int v = (i < n) ? deg[i] : 0;
    t0[tid] = v;
    __syncthreads();
    for (int o = 1; o < 256; o <<= 1) {
        int add = (tid >= o) ? t0[tid - o] : 0;
        __syncthreads();
        t0[tid] += add;
        __syncthreads();
    }
    if (i < n) startv[i] = t0[tid] - v;
    if (tid == 255) bsum[blockIdx.x] = t0[255];
}

// single block of 512: exclusive scan of bsum[nb] in place (nb <= 512)
__global__ void k_scan_bsum(int* __restrict__ bsum, int nb) {
    __shared__ int t0[512];
    int tid = threadIdx.x;
    int v = (tid < nb) ? bsum[tid] : 0;
    t0[tid] = v;
    __syncthreads();
    for (int o = 1; o < 512; o <<= 1) {
        int add = (tid >= o) ? t0[tid - o] : 0;
        __syncthreads();
        t0[tid] += add;
        __syncthreads();
    }
    if (tid < nb) bsum[tid] = t0[tid] - v;
}

__global__ void k_scan_add(int* __restrict__ startv, const int* __restrict__ bsum, int n) {
    int i = blockIdx.x * 256 + threadIdx.x;
    if (i < n) startv[i] += bsum[blockIdx.x];
}

// atomic-free fill: pos = startv[dst] + rank
__global__ void k_fill(const int* __restrict__ src, const int* __restrict__ dst,
                       const int* __restrict__ rank, const int* __restrict__ startv,
                       int* __restrict__ csr, int E) {
    int e = blockIdx.x * 256 + threadIdx.x;
    if (e < E) csr[startv[dst[e]] + rank[e]] = src[e];
}

// ---------------- fused gather + LN ----------------
// agg[d] = q[d] + sum_{s in neigh(d)} q[s]  (registers only)
// b = lrelu(dinv[d]*agg + gcn_b); out = LN(concat[nf, b]) * g + beta (bf16)
// wave per node; 16 independent q-row loads in flight.
template <int CH>
__launch_bounds__(256)
__global__ void k_gln(const int* __restrict__ startv, const int* __restrict__ degv,
                      const int* __restrict__ csr, const unsigned short* __restrict__ q,
                      const unsigned short* __restrict__ nf, const float* __restrict__ dinv,
                      const float* __restrict__ gcn_b, const float* __restrict__ lng,
                      const float* __restrict__ lnb, unsigned short* __restrict__ outp,
                      int ldo, int n) {
    int wv = threadIdx.x >> 6, lane = threadIdx.x & 63;
    int node = blockIdx.x * 4 + wv;
    if (node >= n) return;
    constexpr int V = CH / 64;  // channels per lane (1 or 2)
    float a0, a1 = 0.f;
    {
        const unsigned short* qrow = q + (size_t)node * CH;
        if (V == 1) {
            a0 = b2f(qrow[lane]);
        } else {
            unsigned u = *(const unsigned*)(qrow + lane * 2);
            a0 = __uint_as_float((u & 0xffffu) << 16);
            a1 = __uint_as_float(u & 0xffff0000u);
        }
    }
    int s0 = startv[node], cnt = degv[node];
    for (int c0 = 0; c0 < cnt; c0 += 64) {
        int m = cnt - c0; if (m > 64) m = 64;
        int idx = (lane < m) ? csr[s0 + c0 + lane] : 0;
        for (int j = 0; j < m; j += 16) {
            int lim = m - j;  // wave-uniform
            unsigned uu[16];
#pragma unroll
            for (int t = 0; t < 16; ++t) {
                if (t < lim) {
                    int s = __shfl(idx, j + t);
                    if (V == 1) uu[t] = q[(size_t)s * CH + lane];
                    else uu[t] = *(const unsigned*)(q + (size_t)s * CH + lane * 2);
                }
            }
#pragma unroll
            for (int t = 0; t < 16; ++t) {
                if (t < lim) {
                    if (V == 1) {
                        a0 += __uint_as_float(uu[t] << 16);
                    } else {
                        a0 += __uint_as_float((uu[t] & 0xffffu) << 16);
                        a1 += __uint_as_float(uu[t] & 0xffff0000u);
                    }
                }
            }
        }
    }
    // GCN epilogue + LN
    float di = dinv[node];
    float b0, b1 = 0.f, n0, n1 = 0.f;
    {
        const unsigned short* nrow = nf + (size_t)node * CH;
        if (V == 1) {
            b0 = lrelu01(di * a0 + gcn_b[lane]);
            n0 = b2f(nrow[lane]);
        } else {
            int c = lane * 2;
            b0 = lrelu01(di * a0 + gcn_b[c]);
            b1 = lrelu01(di * a1 + gcn_b[c + 1]);
            unsigned u = *(const unsigned*)(nrow + c);
            n0 = __uint_as_float((u & 0xffffu) << 16);
            n1 = __uint_as_float(u & 0xffff0000u);
        }
    }
    float s = n0 + b0 + n1 + b1;
    float ss = n0 * n0 + b0 * b0 + n1 * n1 + b1 * b1;
#pragma unroll
    for (int off = 32; off > 0; off >>= 1) {
        s += __shfl_xor(s, off);
        ss += __shfl_xor(ss, off);
    }
    const float inv2c = 1.f / (float)(2 * CH);
    float mu = s * inv2c;
    float var = ss * inv2c - mu * mu;
    float rsg = rsqrtf(var + EPSV);
    unsigned short* orow = outp + (size_t)node * ldo;
    if (V == 1) {
        orow[lane] = f2b((n0 - mu) * rsg * lng[lane] + lnb[lane]);
        orow[64 + lane] = f2b((b0 - mu) * rsg * lng[64 + lane] + lnb[64 + lane]);
    } else {
        int c = lane * 2;
        ushort2 oA, oB;
        oA.x = f2b((n0 - mu) * rsg * lng[c] + lnb[c]);
        oA.y = f2b((n1 - mu) * rsg * lng[c + 1] + lnb[c + 1]);
        oB.x = f2b((b0 - mu) * rsg * lng[CH + c] + lnb[CH + c]);
        oB.y = f2b((b1 - mu) * rsg * lng[CH + c + 1] + lnb[CH + c + 1]);
        *(ushort2*)(orow + c) = oA;
        *(ushort2*)(orow + CH + c) = oB;
    }
}

// ---------------- small kernels ----------------

__global__ void k_wconv(const float* __restrict__ s0, const float* __restrict__ s1,
                        const float* __restrict__ s2, const float* __restrict__ s3,
                        const float* __restrict__ s4, const float* __restrict__ s5,
                        const float* __restrict__ s6, const float* __restrict__ s7,
                        unsigned short* __restrict__ dst) {
    int t = blockIdx.x * 256 + threadIdx.x;
    if (t >= 278528) return;
    const float* srcs[8] = {s0, s1, s2, s3, s4, s5, s6, s7};
    const int off[9] = {0, 8192, 139264, 143360, 147456, 163840, 180224, 196608, 278528};
    int seg = 0;
    while (t >= off[seg + 1]) ++seg;
    dst[t] = f2b(srcs[seg][t - off[seg]]);
}

// h1 = relu(x @ c1w.T + c1b) -> bf16 [N,64]; thread per node
__global__ void k_h1(const float* __restrict__ x, const float* __restrict__ w,
                     const float* __restrict__ b, unsigned short* __restrict__ h1, int n) {
    int node = blockIdx.x * 256 + threadIdx.x;
    if (node >= n) return;
    float x0 = x[node * 3], x1 = x[node * 3 + 1], x2 = x[node * 3 + 2];
    unsigned short* o = h1 + (size_t)node * 64;
#pragma unroll
    for (int cp = 0; cp < 8; ++cp) {
        unsigned short tmp[8];
#pragma unroll
        for (int t = 0; t < 8; ++t) {
            int c = cp * 8 + t;
            float v = x0 * w[c * 3] + x1 * w[c * 3 + 1] + x2 * w[c * 3 + 2] + b[c];
            tmp[t] = f2b(fmaxf(v, 0.f));
        }
        *(float4*)(o + cp * 8) = *(float4*)tmp;
    }
}

__global__ void k_murs(const float* __restrict__ sum2, const float* __restrict__ ss2,
                       float* __restrict__ mu2, float* __restrict__ rs2, float invn) {
    int c = threadIdx.x;  // 128
    float m = sum2[c] * invn;
    float var = ss2[c] * invn - m * m;
    mu2[c] = m;
    rs2[c] = rsqrtf(var + EPSV);
}

// A3 = bf16(relu((z2 - mu)*rs)), z2 fp32 [N,128]
__global__ void k_prebn(const float* __restrict__ z, const float* __restrict__ mu,
                        const float* __restrict__ rs, unsigned short* __restrict__ a3,
                        int total) {
    int t = (blockIdx.x * 256 + threadIdx.x) * 4;
    if (t >= total) return;
    int c = t & 127;
    float4 v = *(const float4*)(z + t);
    ushort4 o;
    o.x = f2b(fmaxf((v.x - mu[c + 0]) * rs[c + 0], 0.f));
    o.y = f2b(fmaxf((v.y - mu[c + 1]) * rs[c + 1], 0.f));
    o.z = f2b(fmaxf((v.z - mu[c + 2]) * rs[c + 2], 0.f));
    o.w = f2b(fmaxf((v.w - mu[c + 3]) * rs[c + 3], 0.f));
    *(ushort4*)(a3 + t) = o;
}

// g[c] = relu((max_c - mu_c) * rsqrt(var_c + eps)), c in [0,1024)
__global__ void k_g(const float* __restrict__ sum3, const float* __restrict__ ss3,
                    const unsigned* __restrict__ maxk, float* __restrict__ g, float invn) {
    int c = blockIdx.x * 256 + threadIdx.x;
    float m = sum3[c] * invn;
    float var = ss3[c] * invn - m * m;
    unsigned k = maxk[c];
    unsigned u = (k & 0x80000000u) ? (k & 0x7FFFFFFFu) : ~k;
    g[c] = fmaxf((__uint_as_float(u) - m) * rsqrtf(var + EPSV), 0.f);
}

// fc1: a1[row] = relu(f1w[row,:] @ g + f1b[row]); grid 8 x 256, 4 threads/row
__global__ void k_fc1(const float* __restrict__ g, const float* __restrict__ f1w,
                      const float* __restrict__ f1b, float* __restrict__ a1) {
    int row = blockIdx.x * 64 + (threadIdx.x >> 2);
    int part = threadIdx.x & 3;
    const float* w = f1w + (size_t)row * 1024 + part * 256;
    const float* gg = g + part * 256;
    float s = 0.f;
    for (int k = 0; k < 256; ++k) s = fmaf(w[k], gg[k], s);
    s += __shfl_xor(s, 1); s += __shfl_xor(s, 2);
    if (part == 0) a1[row] = fmaxf(s + f1b[row], 0.f);
}

__launch_bounds__(256)
__global__ void k_fc23(const float* __restrict__ a1, const float* __restrict__ f2w,
                       const float* __restrict__ f2b, const float* __restrict__ f3w,
                       const float* __restrict__ f3b, float* __restrict__ T9) {
    __shared__ float a2[256];
    int tid = threadIdx.x;
    {
        const float* w = f2w + (size_t)tid * 512;
        float s = f2b[tid];
        for (int k = 0; k < 512; ++k) s = fmaf(w[k], a1[k], s);
        a2[tid] = fmaxf(s, 0.f);
    }
    __syncthreads();
    if (tid < 9) {
        const float* w = f3w + (size_t)tid * 256;
        float s = f3b[tid];
        for (int k = 0; k < 256; ++k) s = fmaf(w[k], a2[k], s);
        if (tid == 0 || tid == 4 || tid == 8) s += 1.f;
        T9[tid] = s;
    }
}

// xg = lrelu((x@T) @ conv1w.T + b) -> bf16 into hcat cols 256..; thread per node
__global__ void k_xg(const float* __restrict__ x, const float* __restrict__ T9,
                     const float* __restrict__ w, const float* __restrict__ b,
                     unsigned short* __restrict__ xg, int n) {
    int node = blockIdx.x * 256 + threadIdx.x;
    if (node >= n) return;
    float x0 = x[node * 3], x1 = x[node * 3 + 1], x2 = x[node * 3 + 2];
    float h0 = x0 * T9[0] + x1 * T9[3] + x2 * T9[6];
    float h1 = x0 * T9[1] + x1 * T9[4] + x2 * T9[7];
    float h2 = x0 * T9[2] + x1 * T9[5] + x2 * T9[8];
    unsigned short* o = xg + (size_t)node * 320;
#pragma unroll
    for (int cp = 0; cp < 8; ++cp) {
        unsigned short tmp[8];
#pragma unroll
        for (int t = 0; t < 8; ++t) {
            int c = cp * 8 + t;
            float v = h0 * w[c * 3] + h1 * w[c * 3 + 1] + h2 * w[c * 3 + 2] + b[c];
            tmp[t] = f2b(lrelu01(v));
        }
        *(float4*)(o + cp * 8) = *(float4*)tmp;
    }
}

__global__ void k_const4(const float* __restrict__ pooled, const float* __restrict__ ow,
                         const float* __restrict__ ob, float* __restrict__ c4, float invn) {
    int j = threadIdx.x >> 6, lane = threadIdx.x & 63;
    float s = 0.f;
    for (int c = lane; c < 256; c += 64) s += pooled[c] * invn * ow[j * 320 + c];
#pragma unroll
    for (int off = 32; off > 0; off >>= 1) s += __shfl_down(s, off);
    if (lane == 0) c4[j] = s + ob[j];
}

// out[node] = c4 + xg[node] @ ow[:,256:].T ; thread per node, float4 out
__global__ void k_out(const unsigned short* __restrict__ hcat, const float* __restrict__ ow,
                      const float* __restrict__ c4, float* __restrict__ out, int n) {
    int node = blockIdx.x * 256 + threadIdx.x;
    if (node >= n) return;
    const unsigned short* xgp = hcat + (size_t)node * 320 + 256;
    float s0 = c4[0], s1 = c4[1], s2 = c4[2], s3 = c4[3];
#pragma unroll
    for (int cp = 0; cp < 8; ++cp) {
        float4 raw = *(const float4*)(xgp + cp * 8);
        unsigned short tmp[8];
        *(float4*)tmp = raw;
#pragma unroll
        for (int t = 0; t < 8; ++t) {
            int k = 256 + cp * 8 + t;
            float f = b2f(tmp[t]);
            s0 = fmaf(f, ow[k], s0);
            s1 = fmaf(f, ow[320 + k], s1);
            s2 = fmaf(f, ow[640 + k], s2);
            s3 = fmaf(f, ow[960 + k], s3);
        }
    }
    *(float4*)(out + (size_t)node * 4) = make_float4(s0, s1, s2, s3);
}

// ---------------- MFMA bf16 GEMM (generic) ----------------
enum { MF_BIAS = 1, MF_LRELU = 2, MF_DINV = 4, MF_STOREF = 8, MF_STOREB = 16,
       MF_STATS = 32, MF_COLSUM = 64 };

template <int BN, int MODE>
__launch_bounds__(256)
__global__ void k_mgemm(const unsigned short* __restrict__ A, int lda, int K,
                        const unsigned short* __restrict__ W,  // [C][K]
                        const float* __restrict__ bias,
                        float* __restrict__ OutF, unsigned short* __restrict__ OutB, int ldo,
                        const float* __restrict__ dinv,
                        float* __restrict__ sum_o, float* __restrict__ ss_o,
                        unsigned* __restrict__ maxk_o) {
    constexpr int BM = 128;
    constexpr int LDT = 40;  // ushort stride per 32-k row: 2-way bank alias (free)
    __shared__ unsigned short As[BM * LDT];
    __shared__ unsigned short Ws[BN * LDT];
    __shared__ float redS[2 * 128];
    __shared__ unsigned redM[128];

    const int tid = threadIdx.x;
    const int wid = tid >> 6, lane = tid & 63;
    const int quad = lane >> 4, lrow = lane & 15;
    const int bn0 = blockIdx.x * BM;
    const int bc0 = blockIdx.y * BN;

    constexpr int NI = (BN == 128) ? 4 : 2;
    constexpr int NJ = 4;
    const int wm = (BN == 128) ? (wid & 1) * 64 : wid * 32;
    const int wn = (BN == 128) ? (wid >> 1) * 64 : 0;

    if (MODE & (MF_STATS | MF_COLSUM)) {
        for (int c = tid; c < BN; c += 256) {
            redS[c] = 0.f; redS[128 + c] = 0.f; redM[c] = 0u;
        }
    }

    f32x4 acc[NI][NJ] = {};

    for (int k0 = 0; k0 < K; k0 += 32) {
#pragma unroll
        for (int h = 0; h < 2; ++h) {
            int ch = tid + h * 256;
            int row = ch >> 2, cp = ch & 3;
            const unsigned short* src = A + (size_t)(bn0 + row) * lda + k0 + cp * 8;
            *(float4*)&As[row * LDT + cp * 8] = *(const float4*)src;
        }
#pragma unroll
        for (int h = 0; h < BN / 64; ++h) {
            int ch = tid + h * 256;
            int row = ch >> 2, cp = ch & 3;
            const unsigned short* src = W + (size_t)(bc0 + row) * K + k0 + cp * 8;
            *(float4*)&Ws[row * LDT + cp * 8] = *(const float4*)src;
        }
        __syncthreads();
        frag8 af[NI], bf[NJ];
#pragma unroll
        for (int i = 0; i < NI; ++i)
            af[i] = *(const frag8*)&As[(wm + i * 16 + lrow) * LDT + quad * 8];
#pragma unroll
        for (int j = 0; j < NJ; ++j)
            bf[j] = *(const frag8*)&Ws[(wn + j * 16 + lrow) * LDT + quad * 8];
#pragma unroll
        for (int i = 0; i < NI; ++i)
#pragma unroll
            for (int j = 0; j < NJ; ++j)
                acc[i][j] = __builtin_amdgcn_mfma_f32_16x16x32_bf16(af[i], bf[j], acc[i][j], 0, 0, 0);
        __syncthreads();
    }

    // epilogue: C/D layout col=lane&15, row=quad*4+reg
#pragma unroll
    for (int j = 0; j < NJ; ++j) {
        const int col = bc0 + wn + j * 16 + lrow;
        float bv = (MODE & MF_BIAS) ? bias[col] : 0.f;
        float s = 0.f, q = 0.f, m = -3.4e38f;
#pragma unroll
        for (int i = 0; i < NI; ++i) {
            const int rowb = bn0 + wm + i * 16 + quad * 4;
#pragma unroll
            for (int r = 0; r < 4; ++r) {
                float t = acc[i][j][r] + bv;
                if (MODE & MF_LRELU) t = lrelu01(t);
                if (MODE & MF_DINV) t *= dinv[rowb + r];
                if (MODE & MF_STOREF) OutF[(size_t)(rowb + r) * ldo + col] = t;
                if (MODE & MF_STOREB) OutB[(size_t)(rowb + r) * ldo + col] = f2b(t);
                s += t; q += t * t; m = fmaxf(m, t);
            }
        }
        if (MODE & (MF_STATS | MF_COLSUM)) {
            s += __shfl_xor(s, 16); s += __shfl_xor(s, 32);
            if (MODE & MF_STATS) {
                q += __shfl_xor(q, 16); q += __shfl_xor(q, 32);
                m = fmaxf(m, __shfl_xor(m, 16)); m = fmaxf(m, __shfl_xor(m, 32));
            }
            if (quad == 0) {
                int lc = wn + j * 16 + lrow;
                atomicAdd(&redS[lc], s);
                if (MODE & MF_STATS) {
                    atomicAdd(&redS[128 + lc], q);
                    atomicMax(&redM[lc], fkey(m));
                }
            }
        }
    }
    if (MODE & (MF_STATS | MF_COLSUM)) {
        __syncthreads();
        for (int c = tid; c < BN; c += 256) {
            atomAddF(&sum_o[bc0 + c], redS[c]);
            if (MODE & MF_STATS) {
                atomAddF(&ss_o[bc0 + c], redS[128 + c]);
                atomicMax(&maxk_o[bc0 + c], redM[c]);
            }
        }
    }
}

// ---------------- z3 stats GEMM: A [N,128] resident in LDS, loop 8 channel-blocks ----------------
__launch_bounds__(256)
__global__ void k_z3(const unsigned short* __restrict__ A,   // [N,128] bf16 (A3)
                     const unsigned short* __restrict__ W,   // [1024,128] bf16
                     const float* __restrict__ bias,         // [1024]
                     float* __restrict__ sum_o, float* __restrict__ ss_o,
                     unsigned* __restrict__ maxk_o) {
    constexpr int LDT = 40;
    __shared__ unsigned short As[4 * 128 * LDT];  // [kc][row][LDT]
    __shared__ unsigned short Ws[128 * LDT];
    __shared__ float redS[2 * 128];
    __shared__ unsigned redM[128];

    const int tid = threadIdx.x;
    const int wid = tid >> 6, lane = tid & 63;
    const int quad = lane >> 4, lrow = lane & 15;
    const int bn0 = blockIdx.x * 128;
    const int wm = (wid & 1) * 64;
    const int wn = (wid >> 1) * 64;

    // stage full A tile (128 rows x 128 k): 2048 float4 chunks, 8 per thread
#pragma unroll
    for (int h = 0; h < 8; ++h) {
        int ch = tid + h * 256;
        int row = ch >> 4, cp = ch & 15, kc = cp >> 2, sub = cp & 3;
        *(float4*)&As[kc * 128 * LDT + row * LDT + sub * 8] =
            *(const float4*)(A + (size_t)(bn0 + row) * 128 + cp * 8);
    }

    for (int cb = 0; cb < 8; ++cb) {
        f32x4 acc[4][4] = {};
        for (int kc = 0; kc < 4; ++kc) {
            __syncthreads();  // also covers the initial A-stage on first iteration
#pragma unroll
            for (int h = 0; h < 2; ++h) {
                int ch = tid + h * 256;
                int row = ch >> 2, sub = ch & 3;
                *(float4*)&Ws[row * LDT + sub * 8] =
                    *(const float4*)(W + (size_t)(cb * 128 + row) * 128 + kc * 32 + sub * 8);
            }
            __syncthreads();
            frag8 af[4], bf[4];
#pragma unroll
            for (int i = 0; i < 4; ++i)
                af[i] = *(const frag8*)&As[kc * 128 * LDT + (wm + i * 16 + lrow) * LDT + quad * 8];
#pragma unroll
            for (int j = 0; j < 4; ++j)
                bf[j] = *(const frag8*)&Ws[(wn + j * 16 + lrow) * LDT + quad * 8];
#pragma unroll
            for (int i = 0; i < 4; ++i)
#pragma unroll
                for (int j = 0; j < 4; ++j)
                    acc[i][j] = __builtin_amdgcn_mfma_f32_16x16x32_bf16(af[i], bf[j], acc[i][j], 0, 0, 0);
        }
        // stats epilogue for this cb (raw z3: bias only, no activation)
        __syncthreads();
        for (int c = tid; c < 128; c += 256) {
            redS[c] = 0.f; redS[128 + c] = 0.f; redM[c] = 0u;
        }
        __syncthreads();
#pragma unroll
        for (int j = 0; j < 4; ++j) {
            int lc = wn + j * 16 + lrow;
            float bv = bias[cb * 128 + lc];
            float s = 0.f, q = 0.f, m = -3.4e38f;
#pragma unroll
            for (int i = 0; i < 4; ++i)
#pragma unroll
                for (int r = 0; r < 4; ++r) {
                    float t = acc[i][j][r] + bv;
                    s += t; q += t * t; m = fmaxf(m, t);
                }
            s += __shfl_xor(s, 16); s += __shfl_xor(s, 32);
            q += __shfl_xor(q, 16); q += __shfl_xor(q, 32);
            m = fmaxf(m, __shfl_xor(m, 16)); m = fmaxf(m, __shfl_xor(m, 32));
            if (quad == 0) {
                atomicAdd(&redS[lc], s);
                atomicAdd(&redS[128 + lc], q);
                atomicMax(&redM[lc], fkey(m));
            }
        }
        __syncthreads();
        for (int c = tid; c < 128; c += 256) {
            atomAddF(&sum_o[cb * 128 + c], redS[c]);
            atomAddF(&ss_o[cb * 128 + c], redS[128 + c]);
            atomicMax(&maxk_o[cb * 128 + c], redM[c]);
        }
    }
}

// ---------------- launch ----------------
// Buffer lifetimes (stream-order audited):
//   F1 [N,128]f32: z2 only
//   B1 [N,64] u16: h1 -> nf1
//   B2 [N,128]u16: A3 -> q1 (first N*64) -> hmid -> q2
//   B3 [N,128]u16: hln1 -> nf2
//   H  [N,320]u16: xg cols 256.. (early), LN2 out cols 0..255 (late)

extern "C" void kernel_launch(void* const* d_in, const int* in_sizes, int n_in,
                              void* d_out, int out_size, void* d_ws, size_t ws_size,
                              hipStream_t stream) {
    const float* x   = (const float*)d_in[0];
    const int*   ei  = (const int*)d_in[1];
    const float* c1w = (const float*)d_in[2];  const float* c1b = (const float*)d_in[3];
    const float* c2w = (const float*)d_in[4];  const float* c2b = (const float*)d_in[5];
    const float* c3w = (const float*)d_in[6];  const float* c3b = (const float*)d_in[7];
    const float* f1w = (const float*)d_in[8];  const float* f1b = (const float*)d_in[9];
    const float* f2w = (const float*)d_in[10]; const float* f2b = (const float*)d_in[11];
    const float* f3w = (const float*)d_in[12]; const float* f3b = (const float*)d_in[13];
    const float* cv1w = (const float*)d_in[14]; const float* cv1b = (const float*)d_in[15];
    const float* li1w = (const float*)d_in[16]; const float* li1b = (const float*)d_in[17];
    const float* gc1w = (const float*)d_in[18]; const float* gc1b = (const float*)d_in[19];
    const float* ln1g = (const float*)d_in[20]; const float* ln1b = (const float*)d_in[21];
    const float* cv2w = (const float*)d_in[22]; const float* cv2b = (const float*)d_in[23];
    const float* li2w = (const float*)d_in[24]; const float* li2b = (const float*)d_in[25];
    const float* gc2w = (const float*)d_in[26]; const float* gc2b = (const float*)d_in[27];
    const float* ln2g = (const float*)d_in[28]; const float* ln2b = (const float*)d_in[29];
    const float* cv3w = (const float*)d_in[30]; const float* cv3b = (const float*)d_in[31];
    const float* ow  = (const float*)d_in[32]; const float* ob  = (const float*)d_in[33];
    float* out = (float*)d_out;

    const int N = in_sizes[0] / 3;
    const int E = in_sizes[1] / 2;
    const int* srcI = ei;
    const int* dstI = ei + E;

    char* base = (char*)d_ws;
    size_t off = 0;
    auto take = [&](size_t bytes) -> char* {
        char* p = base + off;
        off = (off + bytes + 255) & ~(size_t)255;
        return p;
    };
    int*   deg    = (int*)  take((size_t)N * 4);
    float* dinv   = (float*)take((size_t)N * 4);
    int*   startv = (int*)  take((size_t)N * 4);
    int*   rank   = (int*)  take((size_t)E * 4);
    int*   csr    = (int*)  take((size_t)E * 4);
    int*   bsum   = (int*)  take(512 * 4);
    float* sm     = (float*)take(8192 * 4);
    unsigned short* WB = (unsigned short*)take(278528 * 2);
    unsigned short* H  = (unsigned short*)take((size_t)N * 320 * 2);
    float* F1 = (float*)take((size_t)N * 128 * 4);
    unsigned short* B1 = (unsigned short*)take((size_t)N * 64 * 2);
    unsigned short* B2 = (unsigned short*)take((size_t)N * 128 * 2);
    unsigned short* B3 = (unsigned short*)take((size_t)N * 128 * 2);

    // bf16 weights inside WB
    unsigned short* c2wb  = WB + 0;
    unsigned short* c3wb  = WB + 8192;
    unsigned short* li1wb = WB + 139264;
    unsigned short* gc1wb = WB + 143360;
    unsigned short* cv2wb = WB + 147456;
    unsigned short* li2wb = WB + 163840;
    unsigned short* gc2wb = WB + 180224;
    unsigned short* cv3wb = WB + 196608;

    // sm layout (floats): [0,3712) zeroed
    float* sum2 = sm + 0;    float* ss2 = sm + 128;
    float* sum3 = sm + 256;  float* ss3 = sm + 1280;
    unsigned* maxk = (unsigned*)(sm + 2304);   // 1024
    float* pooled = sm + 3328;                 // 256
    unsigned* dmax = (unsigned*)(sm + 3584);   // 128 dummy max for z2 stats
    float* mu2 = sm + 3712; float* rs2 = sm + 3840;
    float* T9  = sm + 3968; float* c4 = sm + 3984;
    float* gbuf = sm + 4096;  // 1024
    float* a1   = sm + 5120;  // 512

    const float invn = 1.0f / (float)N;
    const dim3 blk(256);
    const unsigned GX = (unsigned)(N / 128);      // 625
    const unsigned NB = cdivu((unsigned)N, 256);  // 313 scan blocks (<=512)

    hipMemsetAsync(deg, 0, (size_t)N * 4, stream);
    hipMemsetAsync(sm, 0, 3712 * 4, stream);

    // ---- graph prep: deg+rank, dinv, scan, atomic-free fill ----
    k_degrank<<<cdivu(E, 256), blk, 0, stream>>>(dstI, deg, rank, E);
    k_dinv<<<cdivu(N, 256), blk, 0, stream>>>(deg, dinv, N);
    k_scan_local<<<NB, blk, 0, stream>>>(deg, startv, bsum, N);
    k_scan_bsum<<<1, 512, 0, stream>>>(bsum, (int)NB);
    k_scan_add<<<NB, blk, 0, stream>>>(startv, bsum, N);
    k_fill<<<cdivu(E, 256), blk, 0, stream>>>(srcI, dstI, rank, startv, csr, E);

    k_wconv<<<cdivu(278528, 256), blk, 0, stream>>>(c2w, c3w, li1w, gc1w, cv2w, li2w, gc2w, cv3w, WB);

    // ---- TNet ----
    k_h1<<<cdivu((unsigned)N, 256), blk, 0, stream>>>(x, c1w, c1b, B1, N);
    k_mgemm<128, (MF_BIAS | MF_STOREF | MF_STATS)><<<dim3(GX, 1), blk, 0, stream>>>(
        B1, 64, 64, c2wb, c2b, F1, nullptr, 128, nullptr, sum2, ss2, dmax);
    k_murs<<<1, 128, 0, stream>>>(sum2, ss2, mu2, rs2, invn);
    k_prebn<<<cdivu((unsigned)N * 128 / 4, 256), blk, 0, stream>>>(F1, mu2, rs2, B2, N * 128);
    k_z3<<<GX, blk, 0, stream>>>(B2, c3wb, c3b, sum3, ss3, maxk);
    k_g<<<4, blk, 0, stream>>>(sum3, ss3, maxk, gbuf, invn);
    k_fc1<<<8, blk, 0, stream>>>(gbuf, f1w, f1b, a1);
    k_fc23<<<1, blk, 0, stream>>>(a1, f2w, f2b, f3w, f3b, T9);
    k_xg<<<cdivu((unsigned)N, 256), blk, 0, stream>>>(x, T9, cv1w, cv1b, H + 256, N);

    // ---- GCN block 1 (C=64) ----
    k_mgemm<64, (MF_BIAS | MF_LRELU | MF_STOREB)><<<dim3(GX, 1), blk, 0, stream>>>(
        H + 256, 320, 64, li1wb, li1b, nullptr, B1, 64, nullptr, nullptr, nullptr, nullptr);
    k_mgemm<64, (MF_DINV | MF_STOREB)><<<dim3(GX, 1), blk, 0, stream>>>(
        B1, 64, 64, gc1wb, nullptr, nullptr, B2, 64, dinv, nullptr, nullptr, nullptr);
    k_gln<64><<<cdivu((unsigned)N, 4), blk, 0, stream>>>(
        startv, deg, csr, B2, B1, dinv, gc1b, ln1g, ln1b, B3, 128, N);
    k_mgemm<128, (MF_BIAS | MF_LRELU | MF_STOREB)><<<dim3(GX, 1), blk, 0, stream>>>(
        B3, 128, 128, cv2wb, cv2b, nullptr, B2, 128, nullptr, nullptr, nullptr, nullptr);

    // ---- GCN block 2 (C=128) ----
    k_mgemm<128, (MF_BIAS | MF_LRELU | MF_STOREB)><<<dim3(GX, 1), blk, 0, stream>>>(
        B2, 128, 128, li2wb, li2b, nullptr, B3, 128, nullptr, nullptr, nullptr, nullptr);
    k_mgemm<128, (MF_DINV | MF_STOREB)><<<dim3(GX, 1), blk, 0, stream>>>(
        B3, 128, 128, gc2wb, nullptr, nullptr, B2, 128, dinv, nullptr, nullptr, nullptr);
    k_gln<128><<<cdivu((unsigned)N, 4), blk, 0, stream>>>(
        startv, deg, csr, B2, B3, dinv, gc2b, ln2g, ln2b, H, 320, N);

    // ---- conv3 (K=320 -> 256) fused column-sum only ----
    k_mgemm<128, (MF_BIAS | MF_LRELU | MF_COLSUM)><<<dim3(GX, 2), blk, 0, stream>>>(
        H, 320, 320, cv3wb, cv3b, nullptr, nullptr, 0, nullptr, pooled, nullptr, nullptr);

    // ---- head ----
    k_const4<<<1, 256, 0, stream>>>(pooled, ow, ob, c4, invn);
    k_out<<<cdivu((unsigned)N, 256), blk, 0, stream>>>(H, ow, c4, out, N);
}

// Round 7
// 582.627 us; speedup vs baseline: 6.4197x; 1.1084x over previous
//
#include <hip/hip_runtime.h>
#include <cstddef>

#define EPSV 1e-5f

typedef __attribute__((ext_vector_type(8))) short frag8;   // 8 bf16 (4 VGPRs)
typedef __attribute__((ext_vector_type(4))) float f32x4;   // MFMA acc

__device__ __forceinline__ float lrelu01(float v) { return v > 0.f ? v : 0.01f * v; }
__device__ __forceinline__ void atomAddF(float* p, float v) { unsafeAtomicAdd(p, v); }
__device__ __forceinline__ unsigned fkey(float f) {
    unsigned u = __float_as_uint(f);
    return (u & 0x80000000u) ? ~u : (u | 0x80000000u);
}
__device__ __forceinline__ unsigned short f2b(float f) {  // RNE float->bf16
    unsigned u = __float_as_uint(f);
    unsigned r = u + 0x7fffu + ((u >> 16) & 1u);
    return (unsigned short)(r >> 16);
}
__device__ __forceinline__ float b2f(unsigned short h) {
    return __uint_as_float(((unsigned)h) << 16);
}
__device__ __forceinline__ float blo(unsigned u) { return __uint_as_float(u << 16); }
__device__ __forceinline__ float bhi(unsigned u) { return __uint_as_float(u & 0xffff0000u); }

static inline unsigned cdivu(unsigned a, unsigned b) { return (a + b - 1) / b; }

// ---------------- graph prep: degree+rank, dinv, CSR build ----------------

__global__ void k_degrank(const int* __restrict__ dst, int* __restrict__ deg,
                          int* __restrict__ rank, int E) {
    int e = blockIdx.x * 256 + threadIdx.x;
    if (e < E) rank[e] = atomicAdd(&deg[dst[e]], 1);
}

__global__ void k_dinv(const int* __restrict__ deg, float* __restrict__ dinv, int n) {
    int i = blockIdx.x * 256 + threadIdx.x;
    if (i < n) dinv[i] = rsqrtf((float)(deg[i] + 1));  // +1 self loop
}

__global__ void k_scan_local(const int* __restrict__ deg, int* __restrict__ startv,
                             int* __restrict__ bsum, int n) {
    __shared__ int t0[256];
    int tid = threadIdx.x;
    int i = blockIdx.x * 256 + tid;
    int v = (i < n) ? deg[i] : 0;
    t0[tid] = v;
    __syncthreads();
    for (int o = 1; o < 256; o <<= 1) {
        int add = (tid >= o) ? t0[tid - o] : 0;
        __syncthreads();
        t0[tid] += add;
        __syncthreads();
    }
    if (i < n) startv[i] = t0[tid] - v;
    if (tid == 255) bsum[blockIdx.x] = t0[255];
}

__global__ void k_scan_bsum(int* __restrict__ bsum, int nb) {
    __shared__ int t0[512];
    int tid = threadIdx.x;
    int v = (tid < nb) ? bsum[tid] : 0;
    t0[tid] = v;
    __syncthreads();
    for (int o = 1; o < 512; o <<= 1) {
        int add = (tid >= o) ? t0[tid - o] : 0;
        __syncthreads();
        t0[tid] += add;
        __syncthreads();
    }
    if (tid < nb) bsum[tid] = t0[tid] - v;
}

__global__ void k_scan_add(int* __restrict__ startv, const int* __restrict__ bsum, int n) {
    int i = blockIdx.x * 256 + threadIdx.x;
    if (i < n) startv[i] += bsum[blockIdx.x];
}

__global__ void k_fill(const int* __restrict__ src, const int* __restrict__ dst,
                       const int* __restrict__ rank, const int* __restrict__ startv,
                       int* __restrict__ csr, int E) {
    int e = blockIdx.x * 256 + threadIdx.x;
    if (e < E) csr[startv[dst[e]] + rank[e]] = src[e];
}

// ---------------- fused gather + LN (vectorized: 16-lane groups, dwordx4 rows) ----------------
// agg[d] = q[d] + sum_{s in neigh(d)} q[s]; b = lrelu(dinv*agg + gcn_b);
// out = LN(concat[nf,b])*g + beta (bf16). Wave per node. Group g (lane>>4)
// handles rows j === g (mod 4); lane p (lane&15) holds channels [p*CPL, (p+1)*CPL).
template <int CH>
__launch_bounds__(256)
__global__ void k_gln(const int* __restrict__ startv, const int* __restrict__ degv,
                      const int* __restrict__ csr, const unsigned short* __restrict__ q,
                      const unsigned short* __restrict__ nf, const float* __restrict__ dinv,
                      const float* __restrict__ gcn_b, const float* __restrict__ lng,
                      const float* __restrict__ lnb, unsigned short* __restrict__ outp,
                      int ldo, int n) {
    const int wv = threadIdx.x >> 6, lane = threadIdx.x & 63;
    const int g = lane >> 4, p = lane & 15;
    int node = blockIdx.x * 4 + wv;
    if (node >= n) return;
    constexpr int CPL = CH / 16;   // channels per lane: 8 (CH=128) or 4 (CH=64)
    constexpr int DPL = CPL / 2;   // dwords per lane per row: 4 or 2

    float acc[CPL];
#pragma unroll
    for (int k = 0; k < CPL; ++k) acc[k] = 0.f;

    // self row: group 0 only
    {
        unsigned su[DPL];
        const unsigned short* qrow = q + (size_t)node * CH + p * CPL;
        if (DPL == 4) *(uint4*)su = *(const uint4*)qrow;
        else          *(uint2*)su = *(const uint2*)qrow;
        if (g == 0) {
#pragma unroll
            for (int d = 0; d < DPL; ++d) { acc[2 * d] += blo(su[d]); acc[2 * d + 1] += bhi(su[d]); }
        }
    }

    int s0 = startv[node], cnt = degv[node];
    int sidx[4];
#pragma unroll
    for (int t = 0; t < 4; ++t) { int j = t * 4 + g; sidx[t] = (j < cnt) ? csr[s0 + j] : 0; }
    for (int j0 = 0; j0 < cnt; j0 += 16) {
        unsigned buf[4][DPL];
#pragma unroll
        for (int t = 0; t < 4; ++t) {
            const unsigned short* src = q + (size_t)sidx[t] * CH + p * CPL;
            if (DPL == 4) *(uint4*)buf[t] = *(const uint4*)src;
            else          *(uint2*)buf[t] = *(const uint2*)src;
        }
        int nsidx[4];
#pragma unroll
        for (int t = 0; t < 4; ++t) {
            int j = j0 + 16 + t * 4 + g;
            nsidx[t] = (j < cnt) ? csr[s0 + j] : 0;
        }
#pragma unroll
        for (int t = 0; t < 4; ++t) {
            if (j0 + t * 4 + g < cnt) {
#pragma unroll
                for (int d = 0; d < DPL; ++d) {
                    acc[2 * d] += blo(buf[t][d]);
                    acc[2 * d + 1] += bhi(buf[t][d]);
                }
            }
        }
#pragma unroll
        for (int t = 0; t < 4; ++t) sidx[t] = nsidx[t];
    }

    // cross-group reduction: all lanes end with full agg for their channel slice
#pragma unroll
    for (int k = 0; k < CPL; ++k) {
        acc[k] += __shfl_xor(acc[k], 16);
        acc[k] += __shfl_xor(acc[k], 32);
    }

    // GCN epilogue + LN
    float di = dinv[node];
    float nv[CPL], bv[CPL];
    {
        unsigned su[DPL];
        const unsigned short* nrow = nf + (size_t)node * CH + p * CPL;
        if (DPL == 4) *(uint4*)su = *(const uint4*)nrow;
        else          *(uint2*)su = *(const uint2*)nrow;
#pragma unroll
        for (int d = 0; d < DPL; ++d) { nv[2 * d] = blo(su[d]); nv[2 * d + 1] = bhi(su[d]); }
    }
    const float* gb = gcn_b + p * CPL;
#pragma unroll
    for (int k = 0; k < CPL; ++k) bv[k] = lrelu01(di * acc[k] + gb[k]);

    float s = 0.f, ss = 0.f;
#pragma unroll
    for (int k = 0; k < CPL; ++k) { s += nv[k] + bv[k]; ss += nv[k] * nv[k] + bv[k] * bv[k]; }
#pragma unroll
    for (int off = 32; off > 0; off >>= 1) { s += __shfl_xor(s, off); ss += __shfl_xor(ss, off); }
    const float inv = 1.f / (float)(8 * CH);  // 4x group replication * 2*CH channels
    float mu = s * inv;
    float var = ss * inv - mu * mu;
    float rsg = rsqrtf(var + EPSV);

    unsigned short* orow = outp + (size_t)node * ldo;
    if (g == 0) {
        unsigned short tmp[CPL];
        const float* lg = lng + p * CPL; const float* lb = lnb + p * CPL;
#pragma unroll
        for (int k = 0; k < CPL; ++k) tmp[k] = f2b((nv[k] - mu) * rsg * lg[k] + lb[k]);
        if (DPL == 4) *(uint4*)(orow + p * CPL) = *(uint4*)tmp;
        else          *(uint2*)(orow + p * CPL) = *(uint2*)tmp;
    } else if (g == 1) {
        unsigned short tmp[CPL];
        const float* lg = lng + CH + p * CPL; const float* lb = lnb + CH + p * CPL;
#pragma unroll
        for (int k = 0; k < CPL; ++k) tmp[k] = f2b((bv[k] - mu) * rsg * lg[k] + lb[k]);
        if (DPL == 4) *(uint4*)(orow + CH + p * CPL) = *(uint4*)tmp;
        else          *(uint2*)(orow + CH + p * CPL) = *(uint2*)tmp;
    }
}

// ---------------- small kernels ----------------

__global__ void k_wconv(const float* __restrict__ s0, const float* __restrict__ s1,
                        const float* __restrict__ s2, const float* __restrict__ s3,
                        const float* __restrict__ s4, const float* __restrict__ s5,
                        const float* __restrict__ s6, const float* __restrict__ s7,
                        unsigned short* __restrict__ dst) {
    int t = blockIdx.x * 256 + threadIdx.x;
    if (t >= 278528) return;
    const float* srcs[8] = {s0, s1, s2, s3, s4, s5, s6, s7};
    const int off[9] = {0, 8192, 139264, 143360, 147456, 163840, 180224, 196608, 278528};
    int seg = 0;
    while (t >= off[seg + 1]) ++seg;
    dst[t] = f2b(srcs[seg][t - off[seg]]);
}

__global__ void k_h1(const float* __restrict__ x, const float* __restrict__ w,
                     const float* __restrict__ b, unsigned short* __restrict__ h1, int n) {
    int node = blockIdx.x * 256 + threadIdx.x;
    if (node >= n) return;
    float x0 = x[node * 3], x1 = x[node * 3 + 1], x2 = x[node * 3 + 2];
    unsigned short* o = h1 + (size_t)node * 64;
#pragma unroll
    for (int cp = 0; cp < 8; ++cp) {
        unsigned short tmp[8];
#pragma unroll
        for (int t = 0; t < 8; ++t) {
            int c = cp * 8 + t;
            float v = x0 * w[c * 3] + x1 * w[c * 3 + 1] + x2 * w[c * 3 + 2] + b[c];
            tmp[t] = f2b(fmaxf(v, 0.f));
        }
        *(float4*)(o + cp * 8) = *(float4*)tmp;
    }
}

__global__ void k_murs(const float* __restrict__ sum2, const float* __restrict__ ss2,
                       float* __restrict__ mu2, float* __restrict__ rs2, float invn) {
    int c = threadIdx.x;  // 128
    float m = sum2[c] * invn;
    float var = ss2[c] * invn - m * m;
    mu2[c] = m;
    rs2[c] = rsqrtf(var + EPSV);
}

__global__ void k_prebn(const float* __restrict__ z, const float* __restrict__ mu,
                        const float* __restrict__ rs, unsigned short* __restrict__ a3,
                        int total) {
    int t = (blockIdx.x * 256 + threadIdx.x) * 4;
    if (t >= total) return;
    int c = t & 127;
    float4 v = *(const float4*)(z + t);
    ushort4 o;
    o.x = f2b(fmaxf((v.x - mu[c + 0]) * rs[c + 0], 0.f));
    o.y = f2b(fmaxf((v.y - mu[c + 1]) * rs[c + 1], 0.f));
    o.z = f2b(fmaxf((v.z - mu[c + 2]) * rs[c + 2], 0.f));
    o.w = f2b(fmaxf((v.w - mu[c + 3]) * rs[c + 3], 0.f));
    *(ushort4*)(a3 + t) = o;
}

__global__ void k_g(const float* __restrict__ sum3, const float* __restrict__ ss3,
                    const unsigned* __restrict__ maxk, float* __restrict__ g, float invn) {
    int c = blockIdx.x * 256 + threadIdx.x;
    float m = sum3[c] * invn;
    float var = ss3[c] * invn - m * m;
    unsigned k = maxk[c];
    unsigned u = (k & 0x80000000u) ? (k & 0x7FFFFFFFu) : ~k;
    g[c] = fmaxf((__uint_as_float(u) - m) * rsqrtf(var + EPSV), 0.f);
}

__global__ void k_fc1(const float* __restrict__ g, const float* __restrict__ f1w,
                      const float* __restrict__ f1b, float* __restrict__ a1) {
    int row = blockIdx.x * 64 + (threadIdx.x >> 2);
    int part = threadIdx.x & 3;
    const float* w = f1w + (size_t)row * 1024 + part * 256;
    const float* gg = g + part * 256;
    float s = 0.f;
    for (int k = 0; k < 256; ++k) s = fmaf(w[k], gg[k], s);
    s += __shfl_xor(s, 1); s += __shfl_xor(s, 2);
    if (part == 0) a1[row] = fmaxf(s + f1b[row], 0.f);
}

__launch_bounds__(256)
__global__ void k_fc23(const float* __restrict__ a1, const float* __restrict__ f2w,
                       const float* __restrict__ f2b, const float* __restrict__ f3w,
                       const float* __restrict__ f3b, float* __restrict__ T9) {
    __shared__ float a2[256];
    int tid = threadIdx.x;
    {
        const float* w = f2w + (size_t)tid * 512;
        float s = f2b[tid];
        for (int k = 0; k < 512; ++k) s = fmaf(w[k], a1[k], s);
        a2[tid] = fmaxf(s, 0.f);
    }
    __syncthreads();
    if (tid < 9) {
        const float* w = f3w + (size_t)tid * 256;
        float s = f3b[tid];
        for (int k = 0; k < 256; ++k) s = fmaf(w[k], a2[k], s);
        if (tid == 0 || tid == 4 || tid == 8) s += 1.f;
        T9[tid] = s;
    }
}

__global__ void k_xg(const float* __restrict__ x, const float* __restrict__ T9,
                     const float* __restrict__ w, const float* __restrict__ b,
                     unsigned short* __restrict__ xg, int n) {
    int node = blockIdx.x * 256 + threadIdx.x;
    if (node >= n) return;
    float x0 = x[node * 3], x1 = x[node * 3 + 1], x2 = x[node * 3 + 2];
    float h0 = x0 * T9[0] + x1 * T9[3] + x2 * T9[6];
    float h1 = x0 * T9[1] + x1 * T9[4] + x2 * T9[7];
    float h2 = x0 * T9[2] + x1 * T9[5] + x2 * T9[8];
    unsigned short* o = xg + (size_t)node * 320;
#pragma unroll
    for (int cp = 0; cp < 8; ++cp) {
        unsigned short tmp[8];
#pragma unroll
        for (int t = 0; t < 8; ++t) {
            int c = cp * 8 + t;
            float v = h0 * w[c * 3] + h1 * w[c * 3 + 1] + h2 * w[c * 3 + 2] + b[c];
            tmp[t] = f2b(lrelu01(v));
        }
        *(float4*)(o + cp * 8) = *(float4*)tmp;
    }
}

__global__ void k_const4(const float* __restrict__ pooled, const float* __restrict__ ow,
                         const float* __restrict__ ob, float* __restrict__ c4, float invn) {
    int j = threadIdx.x >> 6, lane = threadIdx.x & 63;
    float s = 0.f;
    for (int c = lane; c < 256; c += 64) s += pooled[c] * invn * ow[j * 320 + c];
#pragma unroll
    for (int off = 32; off > 0; off >>= 1) s += __shfl_down(s, off);
    if (lane == 0) c4[j] = s + ob[j];
}

__global__ void k_out(const unsigned short* __restrict__ hcat, const float* __restrict__ ow,
                      const float* __restrict__ c4, float* __restrict__ out, int n) {
    int node = blockIdx.x * 256 + threadIdx.x;
    if (node >= n) return;
    const unsigned short* xgp = hcat + (size_t)node * 320 + 256;
    float s0 = c4[0], s1 = c4[1], s2 = c4[2], s3 = c4[3];
#pragma unroll
    for (int cp = 0; cp < 8; ++cp) {
        float4 raw = *(const float4*)(xgp + cp * 8);
        unsigned short tmp[8];
        *(float4*)tmp = raw;
#pragma unroll
        for (int t = 0; t < 8; ++t) {
            int k = 256 + cp * 8 + t;
            float f = b2f(tmp[t]);
            s0 = fmaf(f, ow[k], s0);
            s1 = fmaf(f, ow[320 + k], s1);
            s2 = fmaf(f, ow[640 + k], s2);
            s3 = fmaf(f, ow[960 + k], s3);
        }
    }
    *(float4*)(out + (size_t)node * 4) = make_float4(s0, s1, s2, s3);
}

// ---------------- MFMA bf16 GEMM (generic) ----------------
enum { MF_BIAS = 1, MF_LRELU = 2, MF_DINV = 4, MF_STOREF = 8, MF_STOREB = 16,
       MF_STATS = 32, MF_COLSUM = 64 };

template <int BN, int MODE>
__launch_bounds__(256)
__global__ void k_mgemm(const unsigned short* __restrict__ A, int lda, int K,
                        const unsigned short* __restrict__ W,  // [C][K]
                        const float* __restrict__ bias,
                        float* __restrict__ OutF, unsigned short* __restrict__ OutB, int ldo,
                        const float* __restrict__ dinv,
                        float* __restrict__ sum_o, float* __restrict__ ss_o,
                        unsigned* __restrict__ maxk_o) {
    constexpr int BM = 128;
    constexpr int LDT = 40;
    __shared__ unsigned short As[BM * LDT];
    __shared__ unsigned short Ws[BN * LDT];
    __shared__ float redS[2 * 128];
    __shared__ unsigned redM[128];

    const int tid = threadIdx.x;
    const int wid = tid >> 6, lane = tid & 63;
    const int quad = lane >> 4, lrow = lane & 15;
    const int bn0 = blockIdx.x * BM;
    const int bc0 = blockIdx.y * BN;

    constexpr int NI = (BN == 128) ? 4 : 2;
    constexpr int NJ = 4;
    const int wm = (BN == 128) ? (wid & 1) * 64 : wid * 32;
    const int wn = (BN == 128) ? (wid >> 1) * 64 : 0;

    if (MODE & (MF_STATS | MF_COLSUM)) {
        for (int c = tid; c < BN; c += 256) {
            redS[c] = 0.f; redS[128 + c] = 0.f; redM[c] = 0u;
        }
    }

    f32x4 acc[NI][NJ] = {};

    for (int k0 = 0; k0 < K; k0 += 32) {
#pragma unroll
        for (int h = 0; h < 2; ++h) {
            int ch = tid + h * 256;
            int row = ch >> 2, cp = ch & 3;
            const unsigned short* src = A + (size_t)(bn0 + row) * lda + k0 + cp * 8;
            *(float4*)&As[row * LDT + cp * 8] = *(const float4*)src;
        }
#pragma unroll
        for (int h = 0; h < BN / 64; ++h) {
            int ch = tid + h * 256;
            int row = ch >> 2, cp = ch & 3;
            const unsigned short* src = W + (size_t)(bc0 + row) * K + k0 + cp * 8;
            *(float4*)&Ws[row * LDT + cp * 8] = *(const float4*)src;
        }
        __syncthreads();
        frag8 af[NI], bf[NJ];
#pragma unroll
        for (int i = 0; i < NI; ++i)
            af[i] = *(const frag8*)&As[(wm + i * 16 + lrow) * LDT + quad * 8];
#pragma unroll
        for (int j = 0; j < NJ; ++j)
            bf[j] = *(const frag8*)&Ws[(wn + j * 16 + lrow) * LDT + quad * 8];
#pragma unroll
        for (int i = 0; i < NI; ++i)
#pragma unroll
            for (int j = 0; j < NJ; ++j)
                acc[i][j] = __builtin_amdgcn_mfma_f32_16x16x32_bf16(af[i], bf[j], acc[i][j], 0, 0, 0);
        __syncthreads();
    }

#pragma unroll
    for (int j = 0; j < NJ; ++j) {
        const int col = bc0 + wn + j * 16 + lrow;
        float bv = (MODE & MF_BIAS) ? bias[col] : 0.f;
        float s = 0.f, q = 0.f, m = -3.4e38f;
#pragma unroll
        for (int i = 0; i < NI; ++i) {
            const int rowb = bn0 + wm + i * 16 + quad * 4;
#pragma unroll
            for (int r = 0; r < 4; ++r) {
                float t = acc[i][j][r] + bv;
                if (MODE & MF_LRELU) t = lrelu01(t);
                if (MODE & MF_DINV) t *= dinv[rowb + r];
                if (MODE & MF_STOREF) OutF[(size_t)(rowb + r) * ldo + col] = t;
                if (MODE & MF_STOREB) OutB[(size_t)(rowb + r) * ldo + col] = f2b(t);
                s += t; q += t * t; m = fmaxf(m, t);
            }
        }
        if (MODE & (MF_STATS | MF_COLSUM)) {
            s += __shfl_xor(s, 16); s += __shfl_xor(s, 32);
            if (MODE & MF_STATS) {
                q += __shfl_xor(q, 16); q += __shfl_xor(q, 32);
                m = fmaxf(m, __shfl_xor(m, 16)); m = fmaxf(m, __shfl_xor(m, 32));
            }
            if (quad == 0) {
                int lc = wn + j * 16 + lrow;
                atomicAdd(&redS[lc], s);
                if (MODE & MF_STATS) {
                    atomicAdd(&redS[128 + lc], q);
                    atomicMax(&redM[lc], fkey(m));
                }
            }
        }
    }
    if (MODE & (MF_STATS | MF_COLSUM)) {
        __syncthreads();
        for (int c = tid; c < BN; c += 256) {
            atomAddF(&sum_o[bc0 + c], redS[c]);
            if (MODE & MF_STATS) {
                atomAddF(&ss_o[bc0 + c], redS[128 + c]);
                atomicMax(&maxk_o[bc0 + c], redM[c]);
            }
        }
    }
}

// ---------------- fused li+gc: nf = lrelu(A@Wli^T + bli); q = (nf@Wgc^T)*dinv ----------------
// BN = C (64 or 128). The 128-row block holds the full nf tile; round-trip via LDS.
// In-place safe when Q aliases A: each block reads only its own rows before writing them.
template <int BN>
__launch_bounds__(256)
__global__ void k_ligc(const unsigned short* __restrict__ A, int lda, int K,
                       const unsigned short* __restrict__ Wli, const float* __restrict__ bli,
                       const unsigned short* __restrict__ Wgc, const float* __restrict__ dinv,
                       unsigned short* __restrict__ NF, int ldnf,
                       unsigned short* __restrict__ Q, int ldq) {
    constexpr int BM = 128;
    constexpr int LDT = 40;
    constexpr int LDT2 = BN + 8;  // full-K nf tile stride (72 or 136); rows 16B-aligned
    __shared__ unsigned short SA[BM * LDT2];  // phase1: stride-40 staging; phase2: nf tile
    __shared__ unsigned short Ws[BN * LDT];

    const int tid = threadIdx.x;
    const int wid = tid >> 6, lane = tid & 63;
    const int quad = lane >> 4, lrow = lane & 15;
    const int bn0 = blockIdx.x * BM;
    constexpr int NI = (BN == 128) ? 4 : 2;
    constexpr int NJ = 4;
    const int wm = (BN == 128) ? (wid & 1) * 64 : wid * 32;
    const int wn = (BN == 128) ? (wid >> 1) * 64 : 0;

    // ---- phase 1: nf ----
    {
        f32x4 acc[NI][NJ] = {};
        for (int k0 = 0; k0 < K; k0 += 32) {
#pragma unroll
            for (int h = 0; h < 2; ++h) {
                int ch = tid + h * 256;
                int row = ch >> 2, cp = ch & 3;
                *(float4*)&SA[row * LDT + cp * 8] =
                    *(const float4*)(A + (size_t)(bn0 + row) * lda + k0 + cp * 8);
            }
#pragma unroll
            for (int h = 0; h < BN / 64; ++h) {
                int ch = tid + h * 256;
                int row = ch >> 2, cp = ch & 3;
                *(float4*)&Ws[row * LDT + cp * 8] =
                    *(const float4*)(Wli + (size_t)row * K + k0 + cp * 8);
            }
            __syncthreads();
            frag8 af[NI], bf[NJ];
#pragma unroll
            for (int i = 0; i < NI; ++i)
                af[i] = *(const frag8*)&SA[(wm + i * 16 + lrow) * LDT + quad * 8];
#pragma unroll
            for (int j = 0; j < NJ; ++j)
                bf[j] = *(const frag8*)&Ws[(wn + j * 16 + lrow) * LDT + quad * 8];
#pragma unroll
            for (int i = 0; i < NI; ++i)
#pragma unroll
                for (int j = 0; j < NJ; ++j)
                    acc[i][j] = __builtin_amdgcn_mfma_f32_16x16x32_bf16(af[i], bf[j], acc[i][j], 0, 0, 0);
            __syncthreads();
        }
        // epilogue 1: store nf (global bf16) + write nf tile into SA (stride LDT2)
#pragma unroll
        for (int j = 0; j < NJ; ++j) {
            const int col = wn + j * 16 + lrow;
            float bv = bli[col];
#pragma unroll
            for (int i = 0; i < NI; ++i) {
                const int rowl = wm + i * 16 + quad * 4;
#pragma unroll
                for (int r = 0; r < 4; ++r) {
                    unsigned short h = f2b(lrelu01(acc[i][j][r] + bv));
                    NF[(size_t)(bn0 + rowl + r) * ldnf + col] = h;
                    SA[(rowl + r) * LDT2 + col] = h;
                }
            }
        }
        __syncthreads();
    }
    // ---- phase 2: q = nf @ Wgc^T, scaled by dinv ----
    {
        f32x4 acc[NI][NJ] = {};
        for (int k0 = 0; k0 < BN; k0 += 32) {
#pragma unroll
            for (int h = 0; h < BN / 64; ++h) {
                int ch = tid + h * 256;
                int row = ch >> 2, cp = ch & 3;
                *(float4*)&Ws[row * LDT + cp * 8] =
                    *(const float4*)(Wgc + (size_t)row * BN + k0 + cp * 8);
            }
            __syncthreads();
            frag8 af[NI], bf[NJ];
#pragma unroll
            for (int i = 0; i < NI; ++i)
                af[i] = *(const frag8*)&SA[(wm + i * 16 + lrow) * LDT2 + k0 + quad * 8];
#pragma unroll
            for (int j = 0; j < NJ; ++j)
                bf[j] = *(const frag8*)&Ws[(wn + j * 16 + lrow) * LDT + quad * 8];
#pragma unroll
            for (int i = 0; i < NI; ++i)
#pragma unroll
                for (int j = 0; j < NJ; ++j)
                    acc[i][j] = __builtin_amdgcn_mfma_f32_16x16x32_bf16(af[i], bf[j], acc[i][j], 0, 0, 0);
            __syncthreads();
        }
#pragma unroll
        for (int j = 0; j < NJ; ++j) {
            const int col = wn + j * 16 + lrow;
#pragma unroll
            for (int i = 0; i < NI; ++i) {
                const int rowb = bn0 + wm + i * 16 + quad * 4;
#pragma unroll
                for (int r = 0; r < 4; ++r) {
                    float t = acc[i][j][r] * dinv[rowb + r];
                    Q[(size_t)(rowb + r) * ldq + col] = f2b(t);
                }
            }
        }
    }
}

// ---------------- z3 stats GEMM: A [N,128] resident in LDS, loop 8 channel-blocks ----------------
__launch_bounds__(256)
__global__ void k_z3(const unsigned short* __restrict__ A,   // [N,128] bf16 (A3)
                     const unsigned short* __restrict__ W,   // [1024,128] bf16
                     const float* __restrict__ bias,         // [1024]
                     float* __restrict__ sum_o, float* __restrict__ ss_o,
                     unsigned* __restrict__ maxk_o) {
    constexpr int LDT = 40;
    __shared__ unsigned short As[4 * 128 * LDT];
    __shared__ unsigned short Ws[128 * LDT];
    __shared__ float redS[2 * 128];
    __shared__ unsigned redM[128];

    const int tid = threadIdx.x;
    const int wid = tid >> 6, lane = tid & 63;
    const int quad = lane >> 4, lrow = lane & 15;
    const int bn0 = blockIdx.x * 128;
    const int wm = (wid & 1) * 64;
    const int wn = (wid >> 1) * 64;

#pragma unroll
    for (int h = 0; h < 8; ++h) {
        int ch = tid + h * 256;
        int row = ch >> 4, cp = ch & 15, kc = cp >> 2, sub = cp & 3;
        *(float4*)&As[kc * 128 * LDT + row * LDT + sub * 8] =
            *(const float4*)(A + (size_t)(bn0 + row) * 128 + cp * 8);
    }

    for (int cb = 0; cb < 8; ++cb) {
        f32x4 acc[4][4] = {};
        for (int kc = 0; kc < 4; ++kc) {
            __syncthreads();
#pragma unroll
            for (int h = 0; h < 2; ++h) {
                int ch = tid + h * 256;
                int row = ch >> 2, sub = ch & 3;
                *(float4*)&Ws[row * LDT + sub * 8] =
                    *(const float4*)(W + (size_t)(cb * 128 + row) * 128 + kc * 32 + sub * 8);
            }
            __syncthreads();
            frag8 af[4], bf[4];
#pragma unroll
            for (int i = 0; i < 4; ++i)
                af[i] = *(const frag8*)&As[kc * 128 * LDT + (wm + i * 16 + lrow) * LDT + quad * 8];
#pragma unroll
            for (int j = 0; j < 4; ++j)
                bf[j] = *(const frag8*)&Ws[(wn + j * 16 + lrow) * LDT + quad * 8];
#pragma unroll
            for (int i = 0; i < 4; ++i)
#pragma unroll
                for (int j = 0; j < 4; ++j)
                    acc[i][j] = __builtin_amdgcn_mfma_f32_16x16x32_bf16(af[i], bf[j], acc[i][j], 0, 0, 0);
        }
        __syncthreads();
        for (int c = tid; c < 128; c += 256) {
            redS[c] = 0.f; redS[128 + c] = 0.f; redM[c] = 0u;
        }
        __syncthreads();
#pragma unroll
        for (int j = 0; j < 4; ++j) {
            int lc = wn + j * 16 + lrow;
            float bv = bias[cb * 128 + lc];
            float s = 0.f, q = 0.f, m = -3.4e38f;
#pragma unroll
            for (int i = 0; i < 4; ++i)
#pragma unroll
                for (int r = 0; r < 4; ++r) {
                    float t = acc[i][j][r] + bv;
                    s += t; q += t * t; m = fmaxf(m, t);
                }
            s += __shfl_xor(s, 16); s += __shfl_xor(s, 32);
            q += __shfl_xor(q, 16); q += __shfl_xor(q, 32);
            m = fmaxf(m, __shfl_xor(m, 16)); m = fmaxf(m, __shfl_xor(m, 32));
            if (quad == 0) {
                atomicAdd(&redS[lc], s);
                atomicAdd(&redS[128 + lc], q);
                atomicMax(&redM[lc], fkey(m));
            }
        }
        __syncthreads();
        for (int c = tid; c < 128; c += 256) {
            atomAddF(&sum_o[cb * 128 + c], redS[c]);
            atomAddF(&ss_o[cb * 128 + c], redS[128 + c]);
            atomicMax(&maxk_o[cb * 128 + c], redM[c]);
        }
    }
}

// ---------------- launch ----------------
// Buffer lifetimes:
//   F1 [N,128]f32: z2 only
//   B1 [N,64] u16: h1 -> nf1
//   B2 [N,128]u16: A3 -> q1 (first N*64) -> hmid -> q2 (in-place over hmid)
//   B3 [N,128]u16: hln1 -> nf2
//   H  [N,320]u16: xg cols 256.. (early), LN2 out cols 0..255 (late)

extern "C" void kernel_launch(void* const* d_in, const int* in_sizes, int n_in,
                              void* d_out, int out_size, void* d_ws, size_t ws_size,
                              hipStream_t stream) {
    const float* x   = (const float*)d_in[0];
    const int*   ei  = (const int*)d_in[1];
    const float* c1w = (const float*)d_in[2];  const float* c1b = (const float*)d_in[3];
    const float* c2w = (const float*)d_in[4];  const float* c2b = (const float*)d_in[5];
    const float* c3w = (const float*)d_in[6];  const float* c3b = (const float*)d_in[7];
    const float* f1w = (const float*)d_in[8];  const float* f1b = (const float*)d_in[9];
    const float* f2w = (const float*)d_in[10]; const float* f2b = (const float*)d_in[11];
    const float* f3w = (const float*)d_in[12]; const float* f3b = (const float*)d_in[13];
    const float* cv1w = (const float*)d_in[14]; const float* cv1b = (const float*)d_in[15];
    const float* li1w = (const float*)d_in[16]; const float* li1b = (const float*)d_in[17];
    const float* gc1w = (const float*)d_in[18]; const float* gc1b = (const float*)d_in[19];
    const float* ln1g = (const float*)d_in[20]; const float* ln1b = (const float*)d_in[21];
    const float* cv2w = (const float*)d_in[22]; const float* cv2b = (const float*)d_in[23];
    const float* li2w = (const float*)d_in[24]; const float* li2b = (const float*)d_in[25];
    const float* gc2w = (const float*)d_in[26]; const float* gc2b = (const float*)d_in[27];
    const float* ln2g = (const float*)d_in[28]; const float* ln2b = (const float*)d_in[29];
    const float* cv3w = (const float*)d_in[30]; const float* cv3b = (const float*)d_in[31];
    const float* ow  = (const float*)d_in[32]; const float* ob  = (const float*)d_in[33];
    float* out = (float*)d_out;

    const int N = in_sizes[0] / 3;
    const int E = in_sizes[1] / 2;
    const int* srcI = ei;
    const int* dstI = ei + E;

    char* base = (char*)d_ws;
    size_t off = 0;
    auto take = [&](size_t bytes) -> char* {
        char* p = base + off;
        off = (off + bytes + 255) & ~(size_t)255;
        return p;
    };
    int*   deg    = (int*)  take((size_t)N * 4);
    float* dinv   = (float*)take((size_t)N * 4);
    int*   startv = (int*)  take((size_t)N * 4);
    int*   rank   = (int*)  take((size_t)E * 4);
    int*   csr    = (int*)  take((size_t)E * 4);
    int*   bsum   = (int*)  take(512 * 4);
    float* sm     = (float*)take(8192 * 4);
    unsigned short* WB = (unsigned short*)take(278528 * 2);
    unsigned short* H  = (unsigned short*)take((size_t)N * 320 * 2);
    float* F1 = (float*)take((size_t)N * 128 * 4);
    unsigned short* B1 = (unsigned short*)take((size_t)N * 64 * 2);
    unsigned short* B2 = (unsigned short*)take((size_t)N * 128 * 2);
    unsigned short* B3 = (unsigned short*)take((size_t)N * 128 * 2);

    unsigned short* c2wb  = WB + 0;
    unsigned short* c3wb  = WB + 8192;
    unsigned short* li1wb = WB + 139264;
    unsigned short* gc1wb = WB + 143360;
    unsigned short* cv2wb = WB + 147456;
    unsigned short* li2wb = WB + 163840;
    unsigned short* gc2wb = WB + 180224;
    unsigned short* cv3wb = WB + 196608;

    float* sum2 = sm + 0;    float* ss2 = sm + 128;
    float* sum3 = sm + 256;  float* ss3 = sm + 1280;
    unsigned* maxk = (unsigned*)(sm + 2304);
    float* pooled = sm + 3328;
    unsigned* dmax = (unsigned*)(sm + 3584);
    float* mu2 = sm + 3712; float* rs2 = sm + 3840;
    float* T9  = sm + 3968; float* c4 = sm + 3984;
    float* gbuf = sm + 4096;
    float* a1   = sm + 5120;

    const float invn = 1.0f / (float)N;
    const dim3 blk(256);
    const unsigned GX = (unsigned)(N / 128);
    const unsigned NB = cdivu((unsigned)N, 256);

    hipMemsetAsync(deg, 0, (size_t)N * 4, stream);
    hipMemsetAsync(sm, 0, 3712 * 4, stream);

    // ---- graph prep ----
    k_degrank<<<cdivu(E, 256), blk, 0, stream>>>(dstI, deg, rank, E);
    k_dinv<<<cdivu(N, 256), blk, 0, stream>>>(deg, dinv, N);
    k_scan_local<<<NB, blk, 0, stream>>>(deg, startv, bsum, N);
    k_scan_bsum<<<1, 512, 0, stream>>>(bsum, (int)NB);
    k_scan_add<<<NB, blk, 0, stream>>>(startv, bsum, N);
    k_fill<<<cdivu(E, 256), blk, 0, stream>>>(srcI, dstI, rank, startv, csr, E);

    k_wconv<<<cdivu(278528, 256), blk, 0, stream>>>(c2w, c3w, li1w, gc1w, cv2w, li2w, gc2w, cv3w, WB);

    // ---- TNet ----
    k_h1<<<cdivu((unsigned)N, 256), blk, 0, stream>>>(x, c1w, c1b, B1, N);
    k_mgemm<128, (MF_BIAS | MF_STOREF | MF_STATS)><<<dim3(GX, 1), blk, 0, stream>>>(
        B1, 64, 64, c2wb, c2b, F1, nullptr, 128, nullptr, sum2, ss2, dmax);
    k_murs<<<1, 128, 0, stream>>>(sum2, ss2, mu2, rs2, invn);
    k_prebn<<<cdivu((unsigned)N * 128 / 4, 256), blk, 0, stream>>>(F1, mu2, rs2, B2, N * 128);
    k_z3<<<GX, blk, 0, stream>>>(B2, c3wb, c3b, sum3, ss3, maxk);
    k_g<<<4, blk, 0, stream>>>(sum3, ss3, maxk, gbuf, invn);
    k_fc1<<<8, blk, 0, stream>>>(gbuf, f1w, f1b, a1);
    k_fc23<<<1, blk, 0, stream>>>(a1, f2w, f2b, f3w, f3b, T9);
    k_xg<<<cdivu((unsigned)N, 256), blk, 0, stream>>>(x, T9, cv1w, cv1b, H + 256, N);

    // ---- GCN block 1 (C=64) ----
    k_ligc<64><<<GX, blk, 0, stream>>>(H + 256, 320, 64, li1wb, li1b, gc1wb, dinv, B1, 64, B2, 64);
    k_gln<64><<<cdivu((unsigned)N, 4), blk, 0, stream>>>(
        startv, deg, csr, B2, B1, dinv, gc1b, ln1g, ln1b, B3, 128, N);
    k_mgemm<128, (MF_BIAS | MF_LRELU | MF_STOREB)><<<dim3(GX, 1), blk, 0, stream>>>(
        B3, 128, 128, cv2wb, cv2b, nullptr, B2, 128, nullptr, nullptr, nullptr, nullptr);

    // ---- GCN block 2 (C=128) ----
    k_ligc<128><<<GX, blk, 0, stream>>>(B2, 128, 128, li2wb, li2b, gc2wb, dinv, B3, 128, B2, 128);
    k_gln<128><<<cdivu((unsigned)N, 4), blk, 0, stream>>>(
        startv, deg, csr, B2, B3, dinv, gc2b, ln2g, ln2b, H, 320, N);

    // ---- conv3 (K=320 -> 256) fused column-sum only ----
    k_mgemm<128, (MF_BIAS | MF_LRELU | MF_COLSUM)><<<dim3(GX, 2), blk, 0, stream>>>(
        H, 320, 320, cv3wb, cv3b, nullptr, nullptr, 0, nullptr, pooled, nullptr, nullptr);

    // ---- head ----
    k_const4<<<1, 256, 0, stream>>>(pooled, ow, ob, c4, invn);
    k_out<<<cdivu((unsigned)N, 256), blk, 0, stream>>>(H, ow, c4, out, N);
}